// Round 5
// baseline (667.500 us; speedup 1.0000x reference)
//
#include <hip/hip_runtime.h>
#include <cmath>
#include <cstdint>
#include <cstddef>

typedef unsigned short bf16_t;
typedef __attribute__((ext_vector_type(8))) short short8;
typedef __attribute__((ext_vector_type(4))) float floatx4;
typedef __attribute__((ext_vector_type(2))) _Float16 half2_t;

__device__ __forceinline__ float bf2f(bf16_t b){
  unsigned int u = ((unsigned int)b) << 16;
  return __uint_as_float(u);
}
__device__ __forceinline__ bf16_t f2bf(float f){
  unsigned int u = __float_as_uint(f);
  unsigned int r = (u + 0x7fffu + ((u >> 16) & 1u)) >> 16;  // RNE
  return (bf16_t)r;
}
__device__ __forceinline__ unsigned int f2bf2(float a, float b){
  return (unsigned int)f2bf(a) | ((unsigned int)f2bf(b) << 16);
}
__device__ __forceinline__ float sigf(float x){ return 1.0f / (1.0f + expf(-x)); }

__device__ __forceinline__ float dot2(half2_t a, half2_t b, float c){
#if __has_builtin(__builtin_amdgcn_fdot2)
  return __builtin_amdgcn_fdot2(a, b, c, false);
#else
  return c + (float)a.x * (float)b.x + (float)a.y * (float)b.y;
#endif
}

__device__ __forceinline__ void gload_lds16(const bf16_t* g, bf16_t* lds){
  __builtin_amdgcn_global_load_lds(
      (const __attribute__((address_space(1))) unsigned int*)g,
      (__attribute__((address_space(3))) unsigned int*)lds, 16, 0, 0);
}

__device__ __forceinline__ void barrier_raw(){
  asm volatile("s_barrier" ::: "memory");
}

// XCD-chunked bijective swizzle (T1, m204 variant). MI355X dispatch round-robins
// blocks across 8 XCDs (XCD = dispatch_id % 8). Remap so each XCD executes a
// CONTIGUOUS logical chunk -> co-XCD blocks share A/B panels and hit in L2.
__device__ __forceinline__ int xcd_chunk_swizzle(int orig, int nwg){
  int q = nwg >> 3, r = nwg & 7;
  int xcd = orig & 7, idx = orig >> 3;
  return (xcd < r ? xcd * (q + 1) : r * (q + 1) + (xcd - r) * q) + idx;
}

// ---------------- mega prep kernel: adds, whh pack, LUTs, stat zero, A2mat K-pad ----------------
__global__ void prep_misc(const float* __restrict__ a1, const float* __restrict__ r1, float* __restrict__ o1,
                          const float* __restrict__ a2, const float* __restrict__ r2, float* __restrict__ o2,
                          const float* __restrict__ bi1, const float* __restrict__ bh1, float* __restrict__ ob1,
                          const float* __restrict__ bi2, const float* __restrict__ bh2, float* __restrict__ ob2,
                          const float* __restrict__ Whh1, half2_t* __restrict__ Wp1,
                          const float* __restrict__ Whh2, half2_t* __restrict__ Wp2,
                          unsigned short* __restrict__ lut1, unsigned short* __restrict__ lut2,
                          float* __restrict__ stats, bf16_t* __restrict__ A2mat){
  int i = blockIdx.x * blockDim.x + threadIdx.x;
  if (i < 8125){ o1[i] = a1[i] + r1[i]; o2[i] = a2[i] + r2[i]; }
  if (i < 384) ob1[i] = bi1[i] + bh1[i];
  if (i < 768) ob2[i] = bi2[i] + bh2[i];
  if (i < 736) stats[i] = 0.f;
  if (i < 18432){                       // pack Whh1 (H=96): Wp[j2*384+t]
    int t = i % 384, j2 = i / 384;
    half2_t w; w.x = (_Float16)Whh1[(size_t)t * 96 + 2 * j2];
    w.y = (_Float16)Whh1[(size_t)t * 96 + 2 * j2 + 1];
    Wp1[i] = w;
  }
  if (i < 73728){                       // pack Whh2 (H=192)
    int t = i % 768, j2 = i / 768;
    half2_t w; w.x = (_Float16)Whh2[(size_t)t * 192 + 2 * j2];
    w.y = (_Float16)Whh2[(size_t)t * 192 + 2 * j2 + 1];
    Wp2[i] = w;
  }
  // levy pair LUTs: flat p -> (i<<8)|j
  if (i < 4560){
    int d = 96, p = i;
    int r = (int)(((2.0 * d - 1.0) - sqrt((2.0 * d - 1.0) * (2.0 * d - 1.0) - 8.0 * (double)p)) * 0.5);
    if (r < 0) r = 0;
    while (r + 1 <= d - 2 && (r + 1) * (d - 1) - ((r + 1) * r) / 2 <= p) ++r;
    while (r > 0 && r * (d - 1) - (r * (r - 1)) / 2 > p) --r;
    int jj = p - (r * (d - 1) - (r * (r - 1)) / 2);
    lut1[p] = (unsigned short)((r << 8) | (r + 1 + jj));
  }
  if (i < 18336){
    int d = 192, p = i;
    int r = (int)(((2.0 * d - 1.0) - sqrt((2.0 * d - 1.0) * (2.0 * d - 1.0) - 8.0 * (double)p)) * 0.5);
    if (r < 0) r = 0;
    while (r + 1 <= d - 2 && (r + 1) * (d - 1) - ((r + 1) * r) / 2 <= p) ++r;
    while (r > 0 && r * (d - 1) - (r * (r - 1)) / 2 > p) --r;
    int jj = p - (r * (d - 1) - (r * (r - 1)) / 2);
    lut2[p] = (unsigned short)((r << 8) | (r + 1 + jj));
  }
  if (i < 160000){                      // A2mat K-pad cols [1248,1280), 5000 rows
    int row = i >> 5, col = 1248 + (i & 31);
    A2mat[(size_t)row * 1280 + col] = 0;
  }
}

// ---------------- three fp32->bf16 pad conversions in ONE dispatch ----------------
__device__ __forceinline__ void f2bf_seg(const float* in, bf16_t* out, int Kin, int Kout, int li){
  int ko8 = Kout >> 3;
  int r = li / ko8, k8 = (li % ko8) << 3;
  uint4 u;
  if (k8 + 8 <= Kin){
    const float4* p = reinterpret_cast<const float4*>(in + (size_t)r * Kin + k8);
    float4 x0 = p[0], x1 = p[1];
    u.x = f2bf2(x0.x, x0.y); u.y = f2bf2(x0.z, x0.w);
    u.z = f2bf2(x1.x, x1.y); u.w = f2bf2(x1.z, x1.w);
  } else {
    u.x = u.y = u.z = u.w = 0u;
  }
  *reinterpret_cast<uint4*>(out + (size_t)r * Kout + k8) = u;
}

__global__ void f2bf_pad8_3(const float* __restrict__ in1, bf16_t* __restrict__ out1, int Kin1, int Kout1, int c1,
                            const float* __restrict__ in2, bf16_t* __restrict__ out2, int Kin2, int Kout2, int c2,
                            const float* __restrict__ in3, bf16_t* __restrict__ out3, int Kin3, int Kout3, int c3){
  int idx = blockIdx.x * blockDim.x + threadIdx.x;
  if (idx < c1){ f2bf_seg(in1, out1, Kin1, Kout1, idx); return; }
  idx -= c1;
  if (idx < c2){ f2bf_seg(in2, out2, Kin2, Kout2, idx); return; }
  idx -= c2;
  if (idx < c3) f2bf_seg(in3, out3, Kin3, Kout3, idx);
}

// ---------------- data batchnorm: x(N,C,T,V,M) -> h1[(nm*C+c)*T+t][V] ----------------
__global__ void data_bn_kernel(const float* __restrict__ x, const float* __restrict__ g,
                               const float* __restrict__ bb, float* __restrict__ h1,
                               int N, int C, int T, int V, int M){
  int ch = blockIdx.x;             // (m*V + v)*C + c
  int m = ch / (V * C);
  int v = (ch / C) % V;
  int c = ch % C;
  int tid = threadIdx.x;
  int cnt = N * T;
  float s = 0.f, s2 = 0.f;
  for (int i = tid; i < cnt; i += 64){
    int n = i / T, t = i % T;
    float val = x[(((size_t)(n * C + c) * T + t) * V + v) * M + m];
    s += val; s2 += val * val;
  }
  for (int off = 32; off; off >>= 1){ s += __shfl_down(s, off); s2 += __shfl_down(s2, off); }
  s = __shfl(s, 0); s2 = __shfl(s2, 0);
  float mean = s / cnt;
  float rstd = rsqrtf(s2 / cnt - mean * mean + 1e-5f);
  float gg = g[ch], bo = bb[ch];
  for (int i = tid; i < cnt; i += 64){
    int n = i / T, t = i % T;
    float val = x[(((size_t)(n * C + c) * T + t) * V + v) * M + m];
    float y = (val - mean) * rstd * gg + bo;
    h1[((size_t)((n * M + m) * C + c) * T + t) * V + v] = y;
  }
}

// ---------------- GCN1 fused: support + W-contract + colstats. block = (nm,t) ----------------
__global__ __launch_bounds__(256)
void gcn1_fused(const float* __restrict__ A, const float* __restrict__ h1,
                const float* __restrict__ W1, const float* __restrict__ b1,
                float* __restrict__ y1, float* __restrict__ ssum, float* __restrict__ ssq, int T){
  __shared__ float h[3][25];
  __shared__ float sup[3][325];
  __shared__ float lsum[96], lsq[96];
  int blk = blockIdx.x;
  int nm = blk / T, t = blk % T;
  int tid = threadIdx.x;
  if (tid < 75){
    int c = tid / 25, v = tid % 25;
    h[c][v] = h1[((size_t)(nm * 3 + c) * T + t) * 25 + v];
  }
  if (tid < 96){ lsum[tid] = 0.f; lsq[tid] = 0.f; }
  __syncthreads();
  for (int w = tid; w < 975; w += 256){
    int c = w / 325, ww = w % 325;
    const float* ar = A + ww * 25;
    float acc = 0.f;
    #pragma unroll
    for (int u = 0; u < 25; ++u) acc += ar[u] * h[c][u];
    sup[c][ww] = acc;
  }
  __syncthreads();
  for (int o2 = tid; o2 < 2400; o2 += 256){
    int v = o2 / 96, o = o2 % 96;
    float acc = b1[o];
    #pragma unroll
    for (int k = 0; k < 13; ++k)
      #pragma unroll
      for (int c = 0; c < 3; ++c)
        acc += W1[o * 39 + k * 3 + c] * sup[c][k * 25 + v];
    y1[((size_t)blk * 25 + v) * 96 + o] = acc;
    atomicAdd(&lsum[o], acc);
    atomicAdd(&lsq[o], acc * acc);
  }
  __syncthreads();
  if (tid < 96){ atomicAdd(&ssum[tid], lsum[tid]); atomicAdd(&ssq[tid], lsq[tid]); }
}

// ---------------- feats with inline BN+relu: reads y-mat + stats, writes bf16 rows ----------------
struct SegTable { int st[50]; int en[50]; };

__global__ void feats_bn_kernel(const float* __restrict__ ymat, const float* __restrict__ sum,
                                const float* __restrict__ sumsq, const float* __restrict__ g,
                                const float* __restrict__ bb, bf16_t* __restrict__ feats,
                                SegTable segs, const unsigned int* __restrict__ lut32,
                                int T, int d, int S, int L, int pairs, int rowlenP, int R){
  __shared__ float pts[4][192];
  int bs = blockIdx.x;
  int b = bs / S, s = bs % S;
  int nm = b / 25, v = b % 25;
  int st = segs.st[s], en = segs.en[s];
  int nt = blockDim.x, tid = threadIdx.x;
  for (int l = 0; l < L; ++l){
    int t = st + l; if (t > en) t = en;
    const float* yrow = ymat + ((size_t)(nm * T + t) * 25 + v) * d;
    for (int i = tid; i < d; i += nt){
      float mean = sum[i] / R;
      float rstd = rsqrtf(sumsq[i] / R - mean * mean + 1e-5f);
      pts[l][i] = fmaxf((yrow[i] - mean) * rstd * g[i] + bb[i], 0.f);
    }
  }
  __syncthreads();
  unsigned int* frow32 = reinterpret_cast<unsigned int*>(feats + (size_t)bs * rowlenP);
  int d2 = d >> 1;
  for (int i2 = tid; i2 < d2; i2 += nt){
    int i = 2 * i2;
    frow32[i2]      = f2bf2(pts[0][i], pts[0][i + 1]);
    frow32[d2 + i2] = f2bf2(pts[L - 1][i] - pts[0][i], pts[L - 1][i + 1] - pts[0][i + 1]);
  }
  int rowlen2 = (2 * d + pairs) >> 1, rowlenP2 = rowlenP >> 1;
  for (int i = tid + rowlen2; i < rowlenP2; i += nt) frow32[i] = 0;  // K pad
  int Lm2 = L - 2;
  unsigned int* lrow32 = frow32 + d;
  int pairs2 = pairs >> 1;
  for (int p2 = tid; p2 < pairs2; p2 += nt){
    unsigned int ee = lut32[p2];
    int i0 = (ee >> 8) & 255, j0 = ee & 255;
    int i1 = ee >> 24, j1 = (ee >> 16) & 255;
    float acc0 = 0.f, acc1 = 0.f;
    for (int l = 1; l <= Lm2; ++l){
      float ri = pts[l][i0] - pts[0][i0], rj = pts[l][j0] - pts[0][j0];
      float di = pts[l + 1][i0] - pts[l][i0], dj = pts[l + 1][j0] - pts[l][j0];
      acc0 += ri * dj - rj * di;
      float ri1 = pts[l][i1] - pts[0][i1], rj1 = pts[l][j1] - pts[0][j1];
      float di1 = pts[l + 1][i1] - pts[l][i1], dj1 = pts[l + 1][j1] - pts[l][j1];
      acc1 += ri1 * dj1 - rj1 * di1;
    }
    lrow32[p2] = f2bf2(0.5f * acc0, 0.5f * acc1);
  }
}

// ---------------- split-K MFMA bf16 NT GEMM, BK=64, XOR-swizzled LDS (128x128, 2-phase) ----------------
// Launched 1-D with flat grid GX*GY*GZ; XCD-chunk swizzled inside (T1).
__global__ __launch_bounds__(256)
void gemm_mfma_nt_split(const bf16_t* __restrict__ A, const bf16_t* __restrict__ B,
                        float* __restrict__ P, int M, int N, int K,
                        int GX, int GY, int GZ){
  __shared__ bf16_t As[128 * 64];
  __shared__ bf16_t Bs[128 * 64];
  const int nwg = GX * GY * GZ;
  const int wg = xcd_chunk_swizzle(blockIdx.x, nwg);
  const int bxi = wg % GX, byi = (wg / GX) % GY, bzi = wg / (GX * GY);
  const int tid = threadIdx.x;
  const int lane = tid & 63, wv = tid >> 6;
  const int bm = bxi * 128, bn = byi * 128;
  const int wr = (wv >> 1) * 64, wc = (wv & 1) * 64;
  const int m_l = lane & 15, q = lane >> 4;

  const int ksteps = K >> 6;
  const int Z = GZ, z = bzi;
  const int per = (ksteps + Z - 1) / Z;
  const int ks0 = z * per;
  const int ks1 = (ks0 + per < ksteps) ? ks0 + per : ksteps;

  const int rlane = lane >> 3;
  const int slane = lane & 7;
  const int colc = (slane ^ rlane) * 8;
  const bf16_t* gA[4]; const bf16_t* gB[4];
  bf16_t* lA[4]; bf16_t* lB[4];
  #pragma unroll
  for (int it = 0; it < 4; ++it){
    int c = it * 4 + wv;
    int rowA = bm + c * 8 + rlane; if (rowA > M - 1) rowA = M - 1;
    int rowB = bn + c * 8 + rlane; if (rowB > N - 1) rowB = N - 1;
    gA[it] = A + (size_t)rowA * K + colc;
    gB[it] = B + (size_t)rowB * K + colc;
    lA[it] = &As[c * 512];
    lB[it] = &Bs[c * 512];
  }
  const int sxor = m_l & 7;

  floatx4 acc[4][4] = {};
  for (int ks = ks0; ks < ks1; ++ks){
    int k0 = ks << 6;
    __syncthreads();
    #pragma unroll
    for (int it = 0; it < 4; ++it){
      gload_lds16(gA[it] + k0, lA[it]);
      gload_lds16(gB[it] + k0, lB[it]);
    }
    __syncthreads();
    #pragma unroll
    for (int half = 0; half < 2; ++half){
      const int scol = ((half * 4 + q) ^ sxor) * 8;
      short8 af[4], bfr[4];
      #pragma unroll
      for (int i = 0; i < 4; ++i){
        af[i]  = *reinterpret_cast<const short8*>(&As[(wr + i * 16 + m_l) * 64 + scol]);
        bfr[i] = *reinterpret_cast<const short8*>(&Bs[(wc + i * 16 + m_l) * 64 + scol]);
      }
      #pragma unroll
      for (int mi = 0; mi < 4; ++mi)
        #pragma unroll
        for (int ni = 0; ni < 4; ++ni)
          acc[mi][ni] = __builtin_amdgcn_mfma_f32_16x16x32_bf16(af[mi], bfr[ni], acc[mi][ni], 0, 0, 0);
    }
  }

  float* Pz = P + (size_t)z * M * N;
  #pragma unroll
  for (int mi = 0; mi < 4; ++mi){
    int row0 = bm + wr + mi * 16 + q * 4;
    #pragma unroll
    for (int r = 0; r < 4; ++r){
      int row = row0 + r;
      if (row < M){
        #pragma unroll
        for (int ni = 0; ni < 4; ++ni){
          int col = bn + wc + ni * 16 + m_l;
          if (col < N) Pz[(size_t)row * N + col] = acc[mi][ni][r];
        }
      }
    }
  }
}

// ---------------- 256x256 8-phase pipelined split-K NT GEMM (T1+T2+T3+T4+T5 + reg-dbuf frags) ----------------
// 512 thr = 8 waves (2M x 4N). LDS 128 KiB: As/Bs = [buf2][kh2][256 rows][32 cols] bf16 planes.
// r5 change: register double-buffered fragments (afA/afB, bfA/bfB). Each phase:
//   {stage next plane; [vmcnt(4)]; barrier; ds_read NEXT phase's frags; setprio; MFMA CURRENT frags; setprio; barrier}
// -> the 8 ds_read_b128 (LDS pipe) overlap the 16 MFMA (matrix pipe) instead of serializing.
// Reads sit AFTER the barrier so vmcnt(4)-guarded planes are globally visible (no cross-wave race).
// vmcnt ledger (2 loads per STG): steady O=4; ph2 vmcnt(4) drains this tile's kh1 (read post-barrier);
// ph4 vmcnt(4) drains next tile's kh0 (read post-barrier). Epilogue: single VMC0 under first MFMA block.
#define VMC4 asm volatile("s_waitcnt vmcnt(4)" ::: "memory")
#define VMC0 asm volatile("s_waitcnt vmcnt(0)" ::: "memory")
#define STG_A8(NB, KH, OFF) { gload_lds16(pA0 + (OFF) + (KH) * 32, dA0 + (NB) * 16384 + (KH) * 8192); \
                              gload_lds16(pA1 + (OFF) + (KH) * 32, dA1 + (NB) * 16384 + (KH) * 8192); }
#define STG_B8(NB, KH, OFF) { gload_lds16(pB0 + (OFF) + (KH) * 32, dB0 + (NB) * 16384 + (KH) * 8192); \
                              gload_lds16(pB1 + (OFF) + (KH) * 32, dB1 + (NB) * 16384 + (KH) * 8192); }
#define READ_AF(DST, BUF, KH, MIB) { \
    const bf16_t* pr_ = As + (BUF) * 16384 + (KH) * 8192 + sA + (MIB) * 512; \
    _Pragma("unroll") \
    for (int i_ = 0; i_ < 4; ++i_) DST[i_] = *reinterpret_cast<const short8*>(pr_ + i_ * 512); }
#define READ_BF(DST, BUF, KH) { \
    const bf16_t* pr_ = Bs + (BUF) * 16384 + (KH) * 8192 + sB; \
    _Pragma("unroll") \
    for (int i_ = 0; i_ < 4; ++i_) DST[i_] = *reinterpret_cast<const short8*>(pr_ + i_ * 512); }
#define MFMA_BLK(AF, BF, MIB) \
    _Pragma("unroll") \
    for (int mi_ = 0; mi_ < 4; ++mi_) \
      _Pragma("unroll") \
      for (int ni_ = 0; ni_ < 4; ++ni_) \
        acc[(MIB) + mi_][ni_] = __builtin_amdgcn_mfma_f32_16x16x32_bf16(AF[mi_], BF[ni_], acc[(MIB) + mi_][ni_], 0, 0, 0);
#define PIPE_PH(STAGE_BLOCK, WAIT_BLOCK, READS_BLOCK, AF, BF, MIB) { \
    STAGE_BLOCK; \
    WAIT_BLOCK; \
    barrier_raw(); \
    READS_BLOCK; \
    __builtin_amdgcn_s_setprio(1); \
    MFMA_BLK(AF, BF, MIB); \
    __builtin_amdgcn_s_setprio(0); \
    barrier_raw(); }

__global__ __launch_bounds__(512, 2)
void gemm_mfma_nt_8ph(const bf16_t* __restrict__ A, const bf16_t* __restrict__ B,
                      float* __restrict__ P, int M, int N, int K,
                      int GX, int GY, int GZ){
  __shared__ bf16_t As[32768];   // 64 KiB: [2][2][256][32]
  __shared__ bf16_t Bs[32768];   // 64 KiB
  const int nwg = GX * GY * GZ;
  const int wg = xcd_chunk_swizzle(blockIdx.x, nwg);
  const int bxi = wg % GX, byi = (wg / GX) % GY, bzi = wg / (GX * GY);
  const int tid = threadIdx.x;
  const int lane = tid & 63, wv = tid >> 6;
  const int wm = wv >> 2, wn = wv & 3;
  const int m_l = lane & 15, q = lane >> 4;
  const int bm = bxi * 256, bn = byi * 256;

  const int ksteps = K >> 6;
  const int z = bzi, Z = GZ;
  const int per = (ksteps + Z - 1) / Z;
  const int ks0 = z * per;
  int ks1 = ks0 + per; if (ks1 > ksteps) ks1 = ksteps;
  if (ks0 >= ks1) return;

  // ---- staging addresses (swizzled global source, linear LDS dest) ----
  const int rlane = lane >> 2, slane = lane & 3;
  const int cg = slane ^ ((rlane >> 1) & 3);
  int rr0 = wv * 16 + rlane, rr1 = (8 + wv) * 16 + rlane;
  int ra0 = bm + rr0; if (ra0 > M - 1) ra0 = M - 1;
  int ra1 = bm + rr1; if (ra1 > M - 1) ra1 = M - 1;
  int rb0 = bn + rr0; if (rb0 > N - 1) rb0 = N - 1;
  int rb1 = bn + rr1; if (rb1 > N - 1) rb1 = N - 1;
  const bf16_t* pA0 = A + (size_t)ra0 * K + cg * 8 + ks0 * 64;
  const bf16_t* pA1 = A + (size_t)ra1 * K + cg * 8 + ks0 * 64;
  const bf16_t* pB0 = B + (size_t)rb0 * K + cg * 8 + ks0 * 64;
  const bf16_t* pB1 = B + (size_t)rb1 * K + cg * 8 + ks0 * 64;
  bf16_t* dA0 = As + wv * 512;
  bf16_t* dA1 = As + (8 + wv) * 512;
  bf16_t* dB0 = Bs + wv * 512;
  bf16_t* dB1 = Bs + (8 + wv) * 512;

  // ---- read base offsets (elems): row stride 32, XOR slot = q ^ ((m_l>>1)&3) ----
  const int sA = (wm * 128 + m_l) * 32 + ((q ^ ((m_l >> 1) & 3)) * 8);
  const int sB = (wn * 64 + m_l) * 32 + ((q ^ ((m_l >> 1) & 3)) * 8);

  short8 afA[4], afB[4], bfA[4], bfB[4];
  floatx4 acc[8][4] = {};

  // ---- prologue: stage tile ks0 into buf0 (order A0,B0,A1,B1) ----
  STG_A8(0, 0, 0); STG_B8(0, 0, 0); STG_A8(0, 1, 0); STG_B8(0, 1, 0);
  VMC4;            // A-kh0 + B-kh0 landed; kh1 (4 loads) stays in flight
  barrier_raw();
  READ_AF(afA, 0, 0, 0);     // initial current set: (buf0, kh0, mib0)
  READ_BF(bfA, 0, 0);

  int buf = 0;
  for (int t = ks0; t < ks1 - 1; ++t){
    const int nb = buf ^ 1;
    // ph1: MFMA(afA,bfA)->acc[0..3]; stage next A-kh0; prefetch afB=(buf,kh0,mib4)
    PIPE_PH(STG_A8(nb, 0, 64), ((void)0),
            { READ_AF(afB, buf, 0, 4); }, afA, bfA, 0);
    // ph2: MFMA(afB,bfA)->acc[4..7]; stage next B-kh0; vmcnt(4) drains this kh1; prefetch kh1 frags
    PIPE_PH(STG_B8(nb, 0, 64), VMC4,
            { READ_AF(afA, buf, 1, 0); READ_BF(bfB, buf, 1); }, afB, bfA, 4);
    // ph3: MFMA(afA,bfB)->acc[0..3]; stage next A-kh1; prefetch afB=(buf,kh1,mib4)
    PIPE_PH(STG_A8(nb, 1, 64), ((void)0),
            { READ_AF(afB, buf, 1, 4); }, afA, bfB, 0);
    // ph4: MFMA(afB,bfB)->acc[4..7]; stage next B-kh1; vmcnt(4) drains next kh0; prefetch next-tile frags
    PIPE_PH(STG_B8(nb, 1, 64), VMC4,
            { READ_AF(afA, nb, 0, 0); READ_BF(bfA, nb, 0); }, afB, bfB, 4);
    pA0 += 64; pA1 += 64; pB0 += 64; pB1 += 64;
    buf = nb;
  }
  // ---- epilogue tile (no stages). O=4 in flight (this tile's kh1). ----
  READ_AF(afB, buf, 0, 4);
  __builtin_amdgcn_s_setprio(1); MFMA_BLK(afA, bfA, 0); __builtin_amdgcn_s_setprio(0);
  VMC0;                       // drain kh1 (own loads) under/after first MFMA block
  barrier_raw();              // all waves drained -> kh1 globally visible
  READ_AF(afA, buf, 1, 0); READ_BF(bfB, buf, 1);
  __builtin_amdgcn_s_setprio(1); MFMA_BLK(afB, bfA, 4); __builtin_amdgcn_s_setprio(0);
  READ_AF(afB, buf, 1, 4);
  __builtin_amdgcn_s_setprio(1);
  MFMA_BLK(afA, bfB, 0);
  MFMA_BLK(afB, bfB, 4);
  __builtin_amdgcn_s_setprio(0);

  // ---- store ----
  float* Pz = P + (size_t)z * M * N;
  #pragma unroll
  for (int mi = 0; mi < 8; ++mi){
    int row0 = bm + wm * 128 + mi * 16 + q * 4;
    #pragma unroll
    for (int r = 0; r < 4; ++r){
      int row = row0 + r;
      if (row < M){
        #pragma unroll
        for (int ni = 0; ni < 4; ++ni){
          int col = bn + wn * 64 + ni * 16 + m_l;
          if (col < N) Pz[(size_t)row * N + col] = acc[mi][ni][r];
        }
      }
    }
  }
}

// ---------------- reduce split partials + bias + colstats (GCN2 path, N=192) ----------------
__global__ __launch_bounds__(256)
void reduce_split_bias_stats(const float* __restrict__ P, const float* __restrict__ bias,
                             float* __restrict__ out, float* __restrict__ ssum, float* __restrict__ ssq,
                             int MN, int N, int Z){
  __shared__ float lsum[192], lsq[192];
  int tid = threadIdx.x;
  if (tid < 192){ lsum[tid] = 0.f; lsq[tid] = 0.f; }
  __syncthreads();
  int i4 = (blockIdx.x * blockDim.x + tid) * 4;
  if (i4 < MN){
    const float4 bv = *reinterpret_cast<const float4*>(bias + (i4 % N));
    float4 s = bv;
    for (int z = 0; z < Z; ++z){
      const float4 p = *reinterpret_cast<const float4*>(P + (size_t)z * MN + i4);
      s.x += p.x; s.y += p.y; s.z += p.z; s.w += p.w;
    }
    *reinterpret_cast<float4*>(out + i4) = s;
    int c0 = i4 % N;
    atomicAdd(&lsum[c0],     s.x); atomicAdd(&lsq[c0],     s.x * s.x);
    atomicAdd(&lsum[c0 + 1], s.y); atomicAdd(&lsq[c0 + 1], s.y * s.y);
    atomicAdd(&lsum[c0 + 2], s.z); atomicAdd(&lsq[c0 + 2], s.z * s.z);
    atomicAdd(&lsum[c0 + 3], s.w); atomicAdd(&lsq[c0 + 3], s.w * s.w);
  }
  __syncthreads();
  if (tid < 192){ atomicAdd(&ssum[tid], lsum[tid]); atomicAdd(&ssq[tid], lsq[tid]); }
}

// ---------------- persistent LSTM: reg f16 weights, fused split-K reduce + segstats, P prefetch ----------------
template <int H2C, int BLK, int Z>
__global__ __launch_bounds__(BLK)
void lstm_kernel(const float* __restrict__ P, const float* __restrict__ bias,
                 const half2_t* __restrict__ Wp, float* __restrict__ out,
                 float* __restrict__ ssum, float* __restrict__ ssq,
                 int S, int MN){
  constexpr int H = 2 * H2C;
  constexpr int H4 = 4 * H;
  __shared__ _Float16 __attribute__((aligned(16))) hsh[H];
  __shared__ float gv[H4];
  __shared__ float ra[BLK / 64], rb[BLK / 64];
  const int b = blockIdx.x, t = threadIdx.x;
  const int lane = t & 63, wid = t >> 6;
  half2_t w[H2C];
  const half2_t* wp = Wp + t;
  #pragma unroll
  for (int j2 = 0; j2 < H2C; ++j2) w[j2] = wp[(size_t)j2 * H4];
  float cc = 0.f;
  if (t < H) hsh[t] = (_Float16)0.f;
  const float bval = bias[t];
  const size_t base = (size_t)b * S * H4 + t;
  float pv0[Z], pv1[Z];
  #pragma unroll
  for (int z = 0; z < Z; ++z) pv0[z] = P[(size_t)z * MN + base];
  #pragma unroll
  for (int z = 0; z < Z; ++z) pv1[z] = P[(size_t)z * MN + base + H4];
  __syncthreads();
  const half2_t* hp = reinterpret_cast<const half2_t*>(hsh);
  for (int s = 0; s < S; ++s){
    float pvn[Z];
    if (s + 2 < S){
      size_t o2 = base + (size_t)(s + 2) * H4;
      #pragma unroll
      for (int z = 0; z < Z; ++z) pvn[z] = P[(size_t)z * MN + o2];
    }
    float a0 = bval, a1 = 0.f, a2 = 0.f, a3 = 0.f;
    float a4 = 0.f, a5 = 0.f, a6 = 0.f, a7 = 0.f;
    #pragma unroll
    for (int z = 0; z < Z; ++z) a0 += pv0[z];
    #pragma unroll
    for (int j2 = 0; j2 < H2C; j2 += 8){
      a0 = dot2(w[j2],     hp[j2],     a0);
      a1 = dot2(w[j2 + 1], hp[j2 + 1], a1);
      a2 = dot2(w[j2 + 2], hp[j2 + 2], a2);
      a3 = dot2(w[j2 + 3], hp[j2 + 3], a3);
      a4 = dot2(w[j2 + 4], hp[j2 + 4], a4);
      a5 = dot2(w[j2 + 5], hp[j2 + 5], a5);
      a6 = dot2(w[j2 + 6], hp[j2 + 6], a6);
      a7 = dot2(w[j2 + 7], hp[j2 + 7], a7);
    }
    gv[t] = ((a0 + a1) + (a2 + a3)) + ((a4 + a5) + (a6 + a7));
    __syncthreads();
    float gvv = 0.f;
    if (t < H){
      float ig = sigf(gv[t]);
      float fg = sigf(gv[H + t]);
      float gg = tanhf(gv[2 * H + t]);
      float og = sigf(gv[3 * H + t]);
      cc = fg * cc + ig * gg;
      float hh = og * tanhf(cc);
      hsh[t] = (_Float16)hh;
      out[((size_t)b * S + s) * H + t] = hh;
      gvv = hh;
    }
    float q1 = gvv, q2 = gvv * gvv;
    for (int off2 = 32; off2; off2 >>= 1){ q1 += __shfl_down(q1, off2); q2 += __shfl_down(q2, off2); }
    if (lane == 0){ ra[wid] = q1; rb[wid] = q2; }
    __syncthreads();
    if (t == 0){
      float sa = 0.f, sb = 0.f;
      #pragma unroll
      for (int ww = 0; ww < BLK / 64; ++ww){ sa += ra[ww]; sb += rb[ww]; }
      atomicAdd(&ssum[s], sa);
      atomicAdd(&ssq[s], sb);
    }
    #pragma unroll
    for (int z = 0; z < Z; ++z){ pv0[z] = pv1[z]; pv1[z] = pvn[z]; }
  }
}

// ---------------- support2 with inline bnseg: A2mat[(nm*S+s)*25+v][k*96+c], stride 1280 ----------------
__global__ void support2_bn(const float* __restrict__ A, const float* __restrict__ lout,
                            const float* __restrict__ ssum, const float* __restrict__ ssq,
                            const float* __restrict__ g, const float* __restrict__ bb,
                            bf16_t* __restrict__ A2mat, int S, int cnt){
  int idx = blockIdx.x * blockDim.x + threadIdx.x;
  int total = 4 * S * 25 * 13 * 96;
  if (idx >= total) return;
  int c = idx % 96;
  int k = (idx / 96) % 13;
  int v = (idx / (96 * 13)) % 25;
  int rs = idx / (96 * 13 * 25);       // nm*S + s
  int s = rs % S, nm = rs / S;
  float mean = ssum[s] / cnt;
  float rstd = rsqrtf(ssq[s] / cnt - mean * mean + 1e-5f);
  float scale = rstd * g[s];
  float shift = bb[s] - mean * scale;
  const float* ar = A + (k * 25 + v) * 25;
  float acc = 0.f;
  #pragma unroll
  for (int u = 0; u < 25; ++u){
    float raw = lout[((size_t)(nm * 25 + u) * S + s) * 96 + c];
    acc += ar[u] * (raw * scale + shift);
  }
  A2mat[((size_t)rs * 25 + v) * 1280 + k * 96 + c] = f2bf(acc);
}

// ---------------- bnseg2 (from sums) + global pool ----------------
__global__ void pool_kernel(const float* __restrict__ lout2, const float* __restrict__ sum,
                            const float* __restrict__ sumsq, const float* __restrict__ g,
                            const float* __restrict__ bb, float* __restrict__ pooled,
                            int S, int H, int scnt){
  int n = blockIdx.x / H;
  int o = blockIdx.x % H;
  float acc = 0.f;
  int cnt = 2 * 25 * S;
  for (int i = threadIdx.x; i < cnt; i += 64){
    int m = i / (25 * S);
    int r = i % (25 * S);
    int v = r / S;
    int s = r % S;
    int b = (n * 2 + m) * 25 + v;
    float val = lout2[((size_t)b * S + s) * H + o];
    float mean = sum[s] / scnt;
    float rstd = rsqrtf(sumsq[s] / scnt - mean * mean + 1e-5f);
    val = (val - mean) * rstd * g[s] + bb[s];
    acc += val;
  }
  for (int off = 32; off; off >>= 1) acc += __shfl_down(acc, off);
  if (threadIdx.x == 0) pooled[n * H + o] = acc / cnt;
}

// ---------------- final FC ----------------
__global__ void fc_kernel(const float* __restrict__ pooled, const float* __restrict__ fcW,
                          const float* __restrict__ fcb, float* __restrict__ outp){
  int idx = blockIdx.x * blockDim.x + threadIdx.x;
  if (idx >= 120) return;
  int n = idx / 60, cls = idx % 60;
  float acc = fcb[cls];
  for (int o = 0; o < 192; ++o) acc += pooled[n * 192 + o] * fcW[cls * 192 + o];
  outp[idx] = acc;
}

// ---------------- host: replicate np.linspace + python round (ties-to-even) ----------------
static void make_segs(int T, int S, SegTable& tab, int& L){
  double step = (double)(T - 1) / (double)S;
  long long tv[51];
  for (int i = 0; i <= S; ++i){
    double v = 1.0 + step * (double)i;
    tv[i] = llrint(v);
  }
  L = 0;
  for (int s = 0; s < S; ++s){
    tab.st[s] = (int)tv[s] - 1;
    tab.en[s] = (int)tv[s + 1] - 1;
    int len = tab.en[s] - tab.st[s] + 1;
    if (len > L) L = len;
  }
  for (int s = S; s < 50; ++s){ tab.st[s] = 0; tab.en[s] = 0; }
  if (L > 4) L = 4;
}

extern "C" void kernel_launch(void* const* d_in, const int* in_sizes, int n_in,
                              void* d_out, int out_size, void* d_ws, size_t ws_size,
                              hipStream_t stream){
  const float* x         = (const float*)d_in[0];
  const float* data_bn_g = (const float*)d_in[2];
  const float* data_bn_b = (const float*)d_in[3];
  const float* A_powers1 = (const float*)d_in[4];
  const float* A_res1    = (const float*)d_in[5];
  const float* W1        = (const float*)d_in[6];
  const float* b1        = (const float*)d_in[7];
  const float* bn1_g     = (const float*)d_in[8];
  const float* bn1_b     = (const float*)d_in[9];
  const float* Wih1      = (const float*)d_in[10];
  const float* Whh1      = (const float*)d_in[11];
  const float* bih1      = (const float*)d_in[12];
  const float* bhh1      = (const float*)d_in[13];
  const float* bnseg1_g  = (const float*)d_in[14];
  const float* bnseg1_b  = (const float*)d_in[15];
  const float* A_powers2 = (const float*)d_in[16];
  const float* A_res2    = (const float*)d_in[17];
  const float* W2        = (const float*)d_in[18];
  const float* b2        = (const float*)d_in[19];
  const float* bn2_g     = (const float*)d_in[20];
  const float* bn2_b     = (const float*)d_in[21];
  const float* Wih2      = (const float*)d_in[22];
  const float* Whh2      = (const float*)d_in[23];
  const float* bih2      = (const float*)d_in[24];
  const float* bhh2      = (const float*)d_in[25];
  const float* bnseg2_g  = (const float*)d_in[26];
  const float* bnseg2_b  = (const float*)d_in[27];
  const float* fcW       = (const float*)d_in[28];
  const float* fcb       = (const float*)d_in[29];
  float* out = (float*)d_out;

  const int N = 2, C = 3, T = 100, V = 25, M = 2, NM = 4;
  const int C1 = 96, C2 = 192;
  const int S1 = 50, S2 = 30;
  const int B = 100;
  const int IN1 = 4752, IN2 = 18720;
  const int IN1P = 4800, IN2P = 18752;  // K padded to %64
  const int P1 = 4560, P2 = 18336;
  const int KG2 = 1248, KG2P = 1280;
  const int Z1 = 5, Z2 = 7, ZG = 4;     // Z2=7: 12x3x7 = 252 blocks = 1/CU for the 8-phase kernel

  size_t off = 0;
  char* base = (char*)d_ws;
  auto alloc = [&](size_t nbytes) -> void* {
    off = (off + 255) & ~(size_t)255;
    void* p = base + off;
    off += nbytes;
    return p;
  };
  float* A1full = (float*)alloc(325 * 25 * 4);
  float* A2full = (float*)alloc(325 * 25 * 4);
  float* h1     = (float*)alloc((size_t)NM * C * T * V * 4);
  float* y1mat  = (float*)alloc((size_t)NM * T * V * C1 * 4);
  float* stats  = (float*)alloc(736 * 4);
  float* st1a = stats, *st1b = stats + 96;
  float* sg1a = stats + 192, *sg1b = stats + 242;
  float* st2a = stats + 292, *st2b = stats + 484;
  float* sg2a = stats + 676, *sg2b = stats + 706;
  float* l1out  = (float*)alloc((size_t)B * S1 * C1 * 4);
  bf16_t* A2mat = (bf16_t*)alloc((size_t)NM * S1 * V * KG2P * 2);
  float* y2mat  = (float*)alloc((size_t)NM * S1 * V * C2 * 4);
  float* l2out  = (float*)alloc((size_t)B * S2 * C2 * 4);
  float* pooled = (float*)alloc(2 * C2 * 4);
  float* bias1  = (float*)alloc(4 * C1 * 4);
  float* bias2  = (float*)alloc(4 * C2 * 4);
  half2_t* Wp1  = (half2_t*)alloc((size_t)(C1 / 2) * 4 * C1 * 4);
  half2_t* Wp2  = (half2_t*)alloc((size_t)(C2 / 2) * 4 * C2 * 4);
  bf16_t* Wih1b = (bf16_t*)alloc((size_t)4 * C1 * IN1P * 2);
  bf16_t* Wih2b = (bf16_t*)alloc((size_t)4 * C2 * IN2P * 2);
  bf16_t* W2b   = (bf16_t*)alloc((size_t)C2 * KG2P * 2);
  unsigned short* lut1 = (unsigned short*)alloc((size_t)P1 * 2);
  unsigned short* lut2 = (unsigned short*)alloc((size_t)P2 * 2);
  size_t pmax = (size_t)Z2 * 3000 * 768;
  {
    size_t p1s = (size_t)Z1 * 5000 * 384; if (p1s > pmax) pmax = p1s;
    size_t pgs = (size_t)ZG * 5000 * 192; if (pgs > pmax) pmax = pgs;
  }
  float* Pbuf = (float*)alloc(pmax * 4);
  bf16_t* feats = (bf16_t*)alloc((size_t)B * S2 * IN2P * 2);
  (void)ws_size; (void)in_sizes; (void)n_in; (void)out_size;

  // 1) prep: adds, whh packs, LUTs, stat zeros, A2mat K-pad
  prep_misc<<<625, 256, 0, stream>>>(A_powers1, A_res1, A1full, A_powers2, A_res2, A2full,
                                     bih1, bhh1, bias1, bih2, bhh2, bias2,
                                     Whh1, Wp1, Whh2, Wp2, lut1, lut2, stats, A2mat);
  // 2) weight bf16 conversion (one dispatch)
  {
    int c1 = 4 * C1 * (IN1P / 8);
    int c2 = 4 * C2 * (IN2P / 8);
    int c3 = C2 * (KG2P / 8);
    int tot = c1 + c2 + c3;
    f2bf_pad8_3<<<(tot + 255) / 256, 256, 0, stream>>>(Wih1, Wih1b, IN1, IN1P, c1,
                                                       Wih2, Wih2b, IN2, IN2P, c2,
                                                       W2, W2b, KG2, KG2P, c3);
  }

  // 3) data BN
  data_bn_kernel<<<M * V * C, 64, 0, stream>>>(x, data_bn_g, data_bn_b, h1, N, C, T, V, M);

  // 4) GCN1 fused (support + contract + stats)
  gcn1_fused<<<NM * T, 256, 0, stream>>>(A1full, h1, W1, b1, y1mat, st1a, st1b, T);

  SegTable seg1, seg2; int L1, L2;
  make_segs(T, S1, seg1, L1);
  make_segs(S1, S2, seg2, L2);

  // 5) feats1 (bn+relu inline)
  feats_bn_kernel<<<B * S1, 256, 0, stream>>>(y1mat, st1a, st1b, bn1_g, bn1_b, feats, seg1,
                                              (const unsigned int*)lut1, T, C1, S1, L1, P1, IN1P,
                                              NM * T * 25);
  // 6) xp1 GEMM + 7) lstm1 (+segstats fused)
  {
    int Mm = B * S1, Nn = 4 * C1;
    int GX = (Mm + 127) / 128, GY = (Nn + 127) / 128;
    gemm_mfma_nt_split<<<GX * GY * Z1, 256, 0, stream>>>(feats, Wih1b, Pbuf, Mm, Nn, IN1P,
                                                         GX, GY, Z1);
    lstm_kernel<48, 384, Z1><<<B, 384, 0, stream>>>(Pbuf, bias1, Wp1, l1out, sg1a, sg1b, S1, Mm * Nn);
  }

  // 8) support2 (+bnseg inline)
  {
    int tot = NM * S1 * 25 * 13 * 96;
    support2_bn<<<(tot + 255) / 256, 256, 0, stream>>>(A2full, l1out, sg1a, sg1b, bnseg1_g,
                                                       bnseg1_b, A2mat, S1, B * C1);
  }
  // 9) GCN2 GEMM + 10) reduce+bias+colstats
  {
    int Mm = NM * S1 * 25, Nn = C2;
    int GX = (Mm + 127) / 128, GY = (Nn + 127) / 128;
    gemm_mfma_nt_split<<<GX * GY * ZG, 256, 0, stream>>>(A2mat, W2b, Pbuf, Mm, Nn, KG2P,
                                                         GX, GY, ZG);
    int MN = Mm * Nn;
    reduce_split_bias_stats<<<(MN / 4 + 255) / 256, 256, 0, stream>>>(Pbuf, b2, y2mat, st2a, st2b,
                                                                      MN, Nn, ZG);
  }

  // 11) feats2 (bn+relu inline)
  feats_bn_kernel<<<B * S2, 256, 0, stream>>>(y2mat, st2a, st2b, bn2_g, bn2_b, feats, seg2,
                                              (const unsigned int*)lut2, S1, C2, S2, L2, P2, IN2P,
                                              NM * S1 * 25);
  // 12) xp2 GEMM (256^2 8-phase pipelined, XCD-chunked) + 13) lstm2 (+segstats fused)
  {
    int Mm = B * S2, Nn = 4 * C2;     // 3000 x 768, K = 18752 (293 K-steps)
    int GX = (Mm + 255) / 256, GY = (Nn + 255) / 256;   // 12 x 3 x 7 = 252 blocks
    gemm_mfma_nt_8ph<<<GX * GY * Z2, 512, 0, stream>>>(feats, Wih2b, Pbuf, Mm, Nn, IN2P,
                                                       GX, GY, Z2);
    lstm_kernel<96, 768, Z2><<<B, 768, 0, stream>>>(Pbuf, bias2, Wp2, l2out, sg2a, sg2b, S2, Mm * Nn);
  }

  // 14) pool, 15) fc
  pool_kernel<<<2 * C2, 64, 0, stream>>>(l2out, sg2a, sg2b, bnseg2_g, bnseg2_b, pooled, S2, C2, B * C2);
  fc_kernel<<<1, 128, 0, stream>>>(pooled, fcW, fcb, out);
}

// Round 7
// 659.161 us; speedup vs baseline: 1.0127x; 1.0127x over previous
//
#include <hip/hip_runtime.h>
#include <cmath>
#include <cstdint>
#include <cstddef>

typedef unsigned short bf16_t;
typedef __attribute__((ext_vector_type(8))) short short8;
typedef __attribute__((ext_vector_type(4))) float floatx4;
typedef __attribute__((ext_vector_type(2))) _Float16 half2_t;

__device__ __forceinline__ float bf2f(bf16_t b){
  unsigned int u = ((unsigned int)b) << 16;
  return __uint_as_float(u);
}
__device__ __forceinline__ bf16_t f2bf(float f){
  unsigned int u = __float_as_uint(f);
  unsigned int r = (u + 0x7fffu + ((u >> 16) & 1u)) >> 16;  // RNE
  return (bf16_t)r;
}
__device__ __forceinline__ unsigned int f2bf2(float a, float b){
  return (unsigned int)f2bf(a) | ((unsigned int)f2bf(b) << 16);
}
__device__ __forceinline__ float sigf(float x){ return 1.0f / (1.0f + expf(-x)); }

__device__ __forceinline__ float dot2(half2_t a, half2_t b, float c){
#if __has_builtin(__builtin_amdgcn_fdot2)
  return __builtin_amdgcn_fdot2(a, b, c, false);
#else
  return c + (float)a.x * (float)b.x + (float)a.y * (float)b.y;
#endif
}

__device__ __forceinline__ void gload_lds16(const bf16_t* g, bf16_t* lds){
  __builtin_amdgcn_global_load_lds(
      (const __attribute__((address_space(1))) unsigned int*)g,
      (__attribute__((address_space(3))) unsigned int*)lds, 16, 0, 0);
}

__device__ __forceinline__ void barrier_raw(){
  asm volatile("s_barrier" ::: "memory");
}

// XCD-chunked bijective swizzle (T1, m204 variant). MI355X dispatch round-robins
// blocks across 8 XCDs (XCD = dispatch_id % 8). Remap so each XCD executes a
// CONTIGUOUS logical chunk -> co-XCD blocks share A/B panels and hit in L2.
__device__ __forceinline__ int xcd_chunk_swizzle(int orig, int nwg){
  int q = nwg >> 3, r = nwg & 7;
  int xcd = orig & 7, idx = orig >> 3;
  return (xcd < r ? xcd * (q + 1) : r * (q + 1) + (xcd - r) * q) + idx;
}

// ---------------- mega prep kernel: adds, whh pack, LUTs, stat zero, A2mat K-pad ----------------
__global__ void prep_misc(const float* __restrict__ a1, const float* __restrict__ r1, float* __restrict__ o1,
                          const float* __restrict__ a2, const float* __restrict__ r2, float* __restrict__ o2,
                          const float* __restrict__ bi1, const float* __restrict__ bh1, float* __restrict__ ob1,
                          const float* __restrict__ bi2, const float* __restrict__ bh2, float* __restrict__ ob2,
                          const float* __restrict__ Whh1, half2_t* __restrict__ Wp1,
                          const float* __restrict__ Whh2, half2_t* __restrict__ Wp2,
                          unsigned short* __restrict__ lut1, unsigned short* __restrict__ lut2,
                          float* __restrict__ stats, bf16_t* __restrict__ A2mat){
  int i = blockIdx.x * blockDim.x + threadIdx.x;
  if (i < 8125){ o1[i] = a1[i] + r1[i]; o2[i] = a2[i] + r2[i]; }
  if (i < 384) ob1[i] = bi1[i] + bh1[i];
  if (i < 768) ob2[i] = bi2[i] + bh2[i];
  if (i < 736) stats[i] = 0.f;
  if (i < 18432){                       // pack Whh1 (H=96): Wp[j2*384+t]
    int t = i % 384, j2 = i / 384;
    half2_t w; w.x = (_Float16)Whh1[(size_t)t * 96 + 2 * j2];
    w.y = (_Float16)Whh1[(size_t)t * 96 + 2 * j2 + 1];
    Wp1[i] = w;
  }
  if (i < 73728){                       // pack Whh2 (H=192)
    int t = i % 768, j2 = i / 768;
    half2_t w; w.x = (_Float16)Whh2[(size_t)t * 192 + 2 * j2];
    w.y = (_Float16)Whh2[(size_t)t * 192 + 2 * j2 + 1];
    Wp2[i] = w;
  }
  // levy pair LUTs: flat p -> (i<<8)|j
  if (i < 4560){
    int d = 96, p = i;
    int r = (int)(((2.0 * d - 1.0) - sqrt((2.0 * d - 1.0) * (2.0 * d - 1.0) - 8.0 * (double)p)) * 0.5);
    if (r < 0) r = 0;
    while (r + 1 <= d - 2 && (r + 1) * (d - 1) - ((r + 1) * r) / 2 <= p) ++r;
    while (r > 0 && r * (d - 1) - (r * (r - 1)) / 2 > p) --r;
    int jj = p - (r * (d - 1) - (r * (r - 1)) / 2);
    lut1[p] = (unsigned short)((r << 8) | (r + 1 + jj));
  }
  if (i < 18336){
    int d = 192, p = i;
    int r = (int)(((2.0 * d - 1.0) - sqrt((2.0 * d - 1.0) * (2.0 * d - 1.0) - 8.0 * (double)p)) * 0.5);
    if (r < 0) r = 0;
    while (r + 1 <= d - 2 && (r + 1) * (d - 1) - ((r + 1) * r) / 2 <= p) ++r;
    while (r > 0 && r * (d - 1) - (r * (r - 1)) / 2 > p) --r;
    int jj = p - (r * (d - 1) - (r * (r - 1)) / 2);
    lut2[p] = (unsigned short)((r << 8) | (r + 1 + jj));
  }
  if (i < 160000){                      // A2mat K-pad cols [1248,1280), 5000 rows
    int row = i >> 5, col = 1248 + (i & 31);
    A2mat[(size_t)row * 1280 + col] = 0;
  }
}

// ---------------- three fp32->bf16 pad conversions in ONE dispatch ----------------
__device__ __forceinline__ void f2bf_seg(const float* in, bf16_t* out, int Kin, int Kout, int li){
  int ko8 = Kout >> 3;
  int r = li / ko8, k8 = (li % ko8) << 3;
  uint4 u;
  if (k8 + 8 <= Kin){
    const float4* p = reinterpret_cast<const float4*>(in + (size_t)r * Kin + k8);
    float4 x0 = p[0], x1 = p[1];
    u.x = f2bf2(x0.x, x0.y); u.y = f2bf2(x0.z, x0.w);
    u.z = f2bf2(x1.x, x1.y); u.w = f2bf2(x1.z, x1.w);
  } else {
    u.x = u.y = u.z = u.w = 0u;
  }
  *reinterpret_cast<uint4*>(out + (size_t)r * Kout + k8) = u;
}

__global__ void f2bf_pad8_3(const float* __restrict__ in1, bf16_t* __restrict__ out1, int Kin1, int Kout1, int c1,
                            const float* __restrict__ in2, bf16_t* __restrict__ out2, int Kin2, int Kout2, int c2,
                            const float* __restrict__ in3, bf16_t* __restrict__ out3, int Kin3, int Kout3, int c3){
  int idx = blockIdx.x * blockDim.x + threadIdx.x;
  if (idx < c1){ f2bf_seg(in1, out1, Kin1, Kout1, idx); return; }
  idx -= c1;
  if (idx < c2){ f2bf_seg(in2, out2, Kin2, Kout2, idx); return; }
  idx -= c2;
  if (idx < c3) f2bf_seg(in3, out3, Kin3, Kout3, idx);
}

// ---------------- data batchnorm: x(N,C,T,V,M) -> h1[(nm*C+c)*T+t][V] ----------------
__global__ void data_bn_kernel(const float* __restrict__ x, const float* __restrict__ g,
                               const float* __restrict__ bb, float* __restrict__ h1,
                               int N, int C, int T, int V, int M){
  int ch = blockIdx.x;             // (m*V + v)*C + c
  int m = ch / (V * C);
  int v = (ch / C) % V;
  int c = ch % C;
  int tid = threadIdx.x;
  int cnt = N * T;
  float s = 0.f, s2 = 0.f;
  for (int i = tid; i < cnt; i += 64){
    int n = i / T, t = i % T;
    float val = x[(((size_t)(n * C + c) * T + t) * V + v) * M + m];
    s += val; s2 += val * val;
  }
  for (int off = 32; off; off >>= 1){ s += __shfl_down(s, off); s2 += __shfl_down(s2, off); }
  s = __shfl(s, 0); s2 = __shfl(s2, 0);
  float mean = s / cnt;
  float rstd = rsqrtf(s2 / cnt - mean * mean + 1e-5f);
  float gg = g[ch], bo = bb[ch];
  for (int i = tid; i < cnt; i += 64){
    int n = i / T, t = i % T;
    float val = x[(((size_t)(n * C + c) * T + t) * V + v) * M + m];
    float y = (val - mean) * rstd * gg + bo;
    h1[((size_t)((n * M + m) * C + c) * T + t) * V + v] = y;
  }
}

// ---------------- GCN1 fused: support + W-contract + colstats. block = (nm,t) ----------------
__global__ __launch_bounds__(256)
void gcn1_fused(const float* __restrict__ A, const float* __restrict__ h1,
                const float* __restrict__ W1, const float* __restrict__ b1,
                float* __restrict__ y1, float* __restrict__ ssum, float* __restrict__ ssq, int T){
  __shared__ float h[3][25];
  __shared__ float sup[3][325];
  __shared__ float lsum[96], lsq[96];
  int blk = blockIdx.x;
  int nm = blk / T, t = blk % T;
  int tid = threadIdx.x;
  if (tid < 75){
    int c = tid / 25, v = tid % 25;
    h[c][v] = h1[((size_t)(nm * 3 + c) * T + t) * 25 + v];
  }
  if (tid < 96){ lsum[tid] = 0.f; lsq[tid] = 0.f; }
  __syncthreads();
  for (int w = tid; w < 975; w += 256){
    int c = w / 325, ww = w % 325;
    const float* ar = A + ww * 25;
    float acc = 0.f;
    #pragma unroll
    for (int u = 0; u < 25; ++u) acc += ar[u] * h[c][u];
    sup[c][ww] = acc;
  }
  __syncthreads();
  for (int o2 = tid; o2 < 2400; o2 += 256){
    int v = o2 / 96, o = o2 % 96;
    float acc = b1[o];
    #pragma unroll
    for (int k = 0; k < 13; ++k)
      #pragma unroll
      for (int c = 0; c < 3; ++c)
        acc += W1[o * 39 + k * 3 + c] * sup[c][k * 25 + v];
    y1[((size_t)blk * 25 + v) * 96 + o] = acc;
    atomicAdd(&lsum[o], acc);
    atomicAdd(&lsq[o], acc * acc);
  }
  __syncthreads();
  if (tid < 96){ atomicAdd(&ssum[tid], lsum[tid]); atomicAdd(&ssq[tid], lsq[tid]); }
}

// ---------------- feats with inline BN+relu: reads y-mat + stats, writes bf16 rows ----------------
struct SegTable { int st[50]; int en[50]; };

__global__ void feats_bn_kernel(const float* __restrict__ ymat, const float* __restrict__ sum,
                                const float* __restrict__ sumsq, const float* __restrict__ g,
                                const float* __restrict__ bb, bf16_t* __restrict__ feats,
                                SegTable segs, const unsigned int* __restrict__ lut32,
                                int T, int d, int S, int L, int pairs, int rowlenP, int R){
  __shared__ float pts[4][192];
  int bs = blockIdx.x;
  int b = bs / S, s = bs % S;
  int nm = b / 25, v = b % 25;
  int st = segs.st[s], en = segs.en[s];
  int nt = blockDim.x, tid = threadIdx.x;
  for (int l = 0; l < L; ++l){
    int t = st + l; if (t > en) t = en;
    const float* yrow = ymat + ((size_t)(nm * T + t) * 25 + v) * d;
    for (int i = tid; i < d; i += nt){
      float mean = sum[i] / R;
      float rstd = rsqrtf(sumsq[i] / R - mean * mean + 1e-5f);
      pts[l][i] = fmaxf((yrow[i] - mean) * rstd * g[i] + bb[i], 0.f);
    }
  }
  __syncthreads();
  unsigned int* frow32 = reinterpret_cast<unsigned int*>(feats + (size_t)bs * rowlenP);
  int d2 = d >> 1;
  for (int i2 = tid; i2 < d2; i2 += nt){
    int i = 2 * i2;
    frow32[i2]      = f2bf2(pts[0][i], pts[0][i + 1]);
    frow32[d2 + i2] = f2bf2(pts[L - 1][i] - pts[0][i], pts[L - 1][i + 1] - pts[0][i + 1]);
  }
  int rowlen2 = (2 * d + pairs) >> 1, rowlenP2 = rowlenP >> 1;
  for (int i = tid + rowlen2; i < rowlenP2; i += nt) frow32[i] = 0;  // K pad
  int Lm2 = L - 2;
  unsigned int* lrow32 = frow32 + d;
  int pairs2 = pairs >> 1;
  for (int p2 = tid; p2 < pairs2; p2 += nt){
    unsigned int ee = lut32[p2];
    int i0 = (ee >> 8) & 255, j0 = ee & 255;
    int i1 = ee >> 24, j1 = (ee >> 16) & 255;
    float acc0 = 0.f, acc1 = 0.f;
    for (int l = 1; l <= Lm2; ++l){
      float ri = pts[l][i0] - pts[0][i0], rj = pts[l][j0] - pts[0][j0];
      float di = pts[l + 1][i0] - pts[l][i0], dj = pts[l + 1][j0] - pts[l][j0];
      acc0 += ri * dj - rj * di;
      float ri1 = pts[l][i1] - pts[0][i1], rj1 = pts[l][j1] - pts[0][j1];
      float di1 = pts[l + 1][i1] - pts[l][i1], dj1 = pts[l + 1][j1] - pts[l][j1];
      acc1 += ri1 * dj1 - rj1 * di1;
    }
    lrow32[p2] = f2bf2(0.5f * acc0, 0.5f * acc1);
  }
}

// ---------------- split-K MFMA bf16 NT GEMM, BK=64, XOR-swizzled LDS (128x128, 2-phase) ----------------
// Launched 1-D with flat grid GX*GY*GZ; XCD-chunk swizzled inside (T1).
__global__ __launch_bounds__(256)
void gemm_mfma_nt_split(const bf16_t* __restrict__ A, const bf16_t* __restrict__ B,
                        float* __restrict__ P, int M, int N, int K,
                        int GX, int GY, int GZ){
  __shared__ bf16_t As[128 * 64];
  __shared__ bf16_t Bs[128 * 64];
  const int nwg = GX * GY * GZ;
  const int wg = xcd_chunk_swizzle(blockIdx.x, nwg);
  const int bxi = wg % GX, byi = (wg / GX) % GY, bzi = wg / (GX * GY);
  const int tid = threadIdx.x;
  const int lane = tid & 63, wv = tid >> 6;
  const int bm = bxi * 128, bn = byi * 128;
  const int wr = (wv >> 1) * 64, wc = (wv & 1) * 64;
  const int m_l = lane & 15, q = lane >> 4;

  const int ksteps = K >> 6;
  const int Z = GZ, z = bzi;
  const int per = (ksteps + Z - 1) / Z;
  const int ks0 = z * per;
  const int ks1 = (ks0 + per < ksteps) ? ks0 + per : ksteps;

  const int rlane = lane >> 3;
  const int slane = lane & 7;
  const int colc = (slane ^ rlane) * 8;
  const bf16_t* gA[4]; const bf16_t* gB[4];
  bf16_t* lA[4]; bf16_t* lB[4];
  #pragma unroll
  for (int it = 0; it < 4; ++it){
    int c = it * 4 + wv;
    int rowA = bm + c * 8 + rlane; if (rowA > M - 1) rowA = M - 1;
    int rowB = bn + c * 8 + rlane; if (rowB > N - 1) rowB = N - 1;
    gA[it] = A + (size_t)rowA * K + colc;
    gB[it] = B + (size_t)rowB * K + colc;
    lA[it] = &As[c * 512];
    lB[it] = &Bs[c * 512];
  }
  const int sxor = m_l & 7;

  floatx4 acc[4][4] = {};
  for (int ks = ks0; ks < ks1; ++ks){
    int k0 = ks << 6;
    __syncthreads();
    #pragma unroll
    for (int it = 0; it < 4; ++it){
      gload_lds16(gA[it] + k0, lA[it]);
      gload_lds16(gB[it] + k0, lB[it]);
    }
    __syncthreads();
    #pragma unroll
    for (int half = 0; half < 2; ++half){
      const int scol = ((half * 4 + q) ^ sxor) * 8;
      short8 af[4], bfr[4];
      #pragma unroll
      for (int i = 0; i < 4; ++i){
        af[i]  = *reinterpret_cast<const short8*>(&As[(wr + i * 16 + m_l) * 64 + scol]);
        bfr[i] = *reinterpret_cast<const short8*>(&Bs[(wc + i * 16 + m_l) * 64 + scol]);
      }
      #pragma unroll
      for (int mi = 0; mi < 4; ++mi)
        #pragma unroll
        for (int ni = 0; ni < 4; ++ni)
          acc[mi][ni] = __builtin_amdgcn_mfma_f32_16x16x32_bf16(af[mi], bfr[ni], acc[mi][ni], 0, 0, 0);
    }
  }

  float* Pz = P + (size_t)z * M * N;
  #pragma unroll
  for (int mi = 0; mi < 4; ++mi){
    int row0 = bm + wr + mi * 16 + q * 4;
    #pragma unroll
    for (int r = 0; r < 4; ++r){
      int row = row0 + r;
      if (row < M){
        #pragma unroll
        for (int ni = 0; ni < 4; ++ni){
          int col = bn + wc + ni * 16 + m_l;
          if (col < N) Pz[(size_t)row * N + col] = acc[mi][ni][r];
        }
      }
    }
  }
}

// ---------------- 256x256 8-phase counted-vmcnt split-K NT GEMM (T1+T2+T3+T4+T5) ----------------
// 512 thr = 8 waves (2M x 4N). LDS 128 KiB: As/Bs = [buf2][kh2][256 rows][32 cols] bf16 planes.
// r6 change vs r4: SINGLE barrier per phase (trailing barrier removed; 4 barriers/tile, was 8).
// Safety ledger: every READ of a plane is separated from that plane's stage-drain by a
// vmcnt(4)+barrier executed by ALL waves (kh0 planes: prev tile ph4; kh1 planes: this tile ph2);
// every STAGE into a plane happens >=1 barrier after the last read of it, and in-flight ds_reads
// retire at the reader's own MFMA lgkmcnt-wait, which precedes the barrier the stager must cross.
// WAR register dependence (same af/bfr arrays) pins MFMA(N) before reads(N+1) within a wave.
#define VMC4 asm volatile("s_waitcnt vmcnt(4)" ::: "memory")
#define VMC0 asm volatile("s_waitcnt vmcnt(0)" ::: "memory")
#define STG_A8(NB, KH, OFF) { gload_lds16(pA0 + (OFF) + (KH) * 32, dA0 + (NB) * 16384 + (KH) * 8192); \
                              gload_lds16(pA1 + (OFF) + (KH) * 32, dA1 + (NB) * 16384 + (KH) * 8192); }
#define STG_B8(NB, KH, OFF) { gload_lds16(pB0 + (OFF) + (KH) * 32, dB0 + (NB) * 16384 + (KH) * 8192); \
                              gload_lds16(pB1 + (OFF) + (KH) * 32, dB1 + (NB) * 16384 + (KH) * 8192); }
#define PH8(BUF, KH, MIB, LOADB, STAGE_BLOCK, WAIT_BLOCK) { \
    const bf16_t* ab_ = As + (BUF) * 16384 + (KH) * 8192 + sA + (MIB) * 512; \
    _Pragma("unroll") \
    for (int i_ = 0; i_ < 4; ++i_) af[i_] = *reinterpret_cast<const short8*>(ab_ + i_ * 512); \
    if (LOADB){ \
      const bf16_t* bb_ = Bs + (BUF) * 16384 + (KH) * 8192 + sB; \
      _Pragma("unroll") \
      for (int i_ = 0; i_ < 4; ++i_) bfr[i_] = *reinterpret_cast<const short8*>(bb_ + i_ * 512); \
    } \
    STAGE_BLOCK; \
    WAIT_BLOCK; \
    barrier_raw(); \
    __builtin_amdgcn_s_setprio(1); \
    _Pragma("unroll") \
    for (int mi_ = 0; mi_ < 4; ++mi_) \
      _Pragma("unroll") \
      for (int ni_ = 0; ni_ < 4; ++ni_) \
        acc[(MIB) + mi_][ni_] = __builtin_amdgcn_mfma_f32_16x16x32_bf16(af[mi_], bfr[ni_], acc[(MIB) + mi_][ni_], 0, 0, 0); \
    __builtin_amdgcn_s_setprio(0); \
  }

__global__ __launch_bounds__(512, 2)
void gemm_mfma_nt_8ph(const bf16_t* __restrict__ A, const bf16_t* __restrict__ B,
                      float* __restrict__ P, int M, int N, int K,
                      int GX, int GY, int GZ){
  __shared__ bf16_t As[32768];   // 64 KiB: [2][2][256][32]
  __shared__ bf16_t Bs[32768];   // 64 KiB
  const int nwg = GX * GY * GZ;
  const int wg = xcd_chunk_swizzle(blockIdx.x, nwg);
  const int bxi = wg % GX, byi = (wg / GX) % GY, bzi = wg / (GX * GY);
  const int tid = threadIdx.x;
  const int lane = tid & 63, wv = tid >> 6;
  const int wm = wv >> 2, wn = wv & 3;
  const int m_l = lane & 15, q = lane >> 4;
  const int bm = bxi * 256, bn = byi * 256;

  const int ksteps = K >> 6;
  const int z = bzi, Z = GZ;
  const int per = (ksteps + Z - 1) / Z;
  const int ks0 = z * per;
  int ks1 = ks0 + per; if (ks1 > ksteps) ks1 = ksteps;
  if (ks0 >= ks1) return;

  // ---- staging addresses (swizzled global source, linear LDS dest) ----
  const int rlane = lane >> 2, slane = lane & 3;
  const int cg = slane ^ ((rlane >> 1) & 3);
  int rr0 = wv * 16 + rlane, rr1 = (8 + wv) * 16 + rlane;
  int ra0 = bm + rr0; if (ra0 > M - 1) ra0 = M - 1;
  int ra1 = bm + rr1; if (ra1 > M - 1) ra1 = M - 1;
  int rb0 = bn + rr0; if (rb0 > N - 1) rb0 = N - 1;
  int rb1 = bn + rr1; if (rb1 > N - 1) rb1 = N - 1;
  const bf16_t* pA0 = A + (size_t)ra0 * K + cg * 8 + ks0 * 64;
  const bf16_t* pA1 = A + (size_t)ra1 * K + cg * 8 + ks0 * 64;
  const bf16_t* pB0 = B + (size_t)rb0 * K + cg * 8 + ks0 * 64;
  const bf16_t* pB1 = B + (size_t)rb1 * K + cg * 8 + ks0 * 64;
  bf16_t* dA0 = As + wv * 512;
  bf16_t* dA1 = As + (8 + wv) * 512;
  bf16_t* dB0 = Bs + wv * 512;
  bf16_t* dB1 = Bs + (8 + wv) * 512;

  // ---- read base offsets (elems): row stride 32, XOR slot = q ^ ((m_l>>1)&3) ----
  const int sA = (wm * 128 + m_l) * 32 + ((q ^ ((m_l >> 1) & 3)) * 8);
  const int sB = (wn * 64 + m_l) * 32 + ((q ^ ((m_l >> 1) & 3)) * 8);

  short8 af[4], bfr[4];
  floatx4 acc[8][4] = {};

  // ---- prologue: stage tile ks0 into buf0 (order A0,B0,A1,B1) ----
  STG_A8(0, 0, 0); STG_B8(0, 0, 0); STG_A8(0, 1, 0); STG_B8(0, 1, 0);
  VMC4;            // A-kh0 + B-kh0 landed; kh1 (4 loads) stays in flight
  barrier_raw();

  int buf = 0;
  for (int t = ks0; t < ks1 - 1; ++t){
    const int nb = buf ^ 1;
    // ph1: compute kh0 mi0-3; issue next A-kh0
    PH8(buf, 0, 0, true,  STG_A8(nb, 0, 64), ((void)0));
    // ph2: compute kh0 mi4-7; issue next B-kh0; vmcnt(4) -> this tile's kh1 landed
    PH8(buf, 0, 4, false, STG_B8(nb, 0, 64), VMC4);
    // ph3: compute kh1 mi0-3; issue next A-kh1
    PH8(buf, 1, 0, true,  STG_A8(nb, 1, 64), ((void)0));
    // ph4: compute kh1 mi4-7; issue next B-kh1; vmcnt(4) -> next tile's kh0 landed
    PH8(buf, 1, 4, false, STG_B8(nb, 1, 64), VMC4);
    pA0 += 64; pA1 += 64; pB0 += 64; pB1 += 64;
    buf = nb;
  }
  // ---- epilogue tile (no stages): drain remaining 4 loads before kh1 ----
  PH8(buf, 0, 0, true,  ((void)0), ((void)0));
  PH8(buf, 0, 4, false, ((void)0), VMC0);
  PH8(buf, 1, 0, true,  ((void)0), ((void)0));
  PH8(buf, 1, 4, false, ((void)0), ((void)0));

  // ---- store ----
  float* Pz = P + (size_t)z * M * N;
  #pragma unroll
  for (int mi = 0; mi < 8; ++mi){
    int row0 = bm + wm * 128 + mi * 16 + q * 4;
    #pragma unroll
    for (int r = 0; r < 4; ++r){
      int row = row0 + r;
      if (row < M){
        #pragma unroll
        for (int ni = 0; ni < 4; ++ni){
          int col = bn + wn * 64 + ni * 16 + m_l;
          if (col < N) Pz[(size_t)row * N + col] = acc[mi][ni][r];
        }
      }
    }
  }
}

// ---------------- reduce split partials + bias + colstats (GCN2 path, N=192) ----------------
__global__ __launch_bounds__(256)
void reduce_split_bias_stats(const float* __restrict__ P, const float* __restrict__ bias,
                             float* __restrict__ out, float* __restrict__ ssum, float* __restrict__ ssq,
                             int MN, int N, int Z){
  __shared__ float lsum[192], lsq[192];
  int tid = threadIdx.x;
  if (tid < 192){ lsum[tid] = 0.f; lsq[tid] = 0.f; }
  __syncthreads();
  int i4 = (blockIdx.x * blockDim.x + tid) * 4;
  if (i4 < MN){
    const float4 bv = *reinterpret_cast<const float4*>(bias + (i4 % N));
    float4 s = bv;
    for (int z = 0; z < Z; ++z){
      const float4 p = *reinterpret_cast<const float4*>(P + (size_t)z * MN + i4);
      s.x += p.x; s.y += p.y; s.z += p.z; s.w += p.w;
    }
    *reinterpret_cast<float4*>(out + i4) = s;
    int c0 = i4 % N;
    atomicAdd(&lsum[c0],     s.x); atomicAdd(&lsq[c0],     s.x * s.x);
    atomicAdd(&lsum[c0 + 1], s.y); atomicAdd(&lsq[c0 + 1], s.y * s.y);
    atomicAdd(&lsum[c0 + 2], s.z); atomicAdd(&lsq[c0 + 2], s.z * s.z);
    atomicAdd(&lsum[c0 + 3], s.w); atomicAdd(&lsq[c0 + 3], s.w * s.w);
  }
  __syncthreads();
  if (tid < 192){ atomicAdd(&ssum[tid], lsum[tid]); atomicAdd(&ssq[tid], lsq[tid]); }
}

// ---------------- persistent LSTM: reg f16 weights, fused split-K reduce + segstats, P prefetch ----------------
template <int H2C, int BLK, int Z>
__global__ __launch_bounds__(BLK)
void lstm_kernel(const float* __restrict__ P, const float* __restrict__ bias,
                 const half2_t* __restrict__ Wp, float* __restrict__ out,
                 float* __restrict__ ssum, float* __restrict__ ssq,
                 int S, int MN){
  constexpr int H = 2 * H2C;
  constexpr int H4 = 4 * H;
  __shared__ _Float16 __attribute__((aligned(16))) hsh[H];
  __shared__ float gv[H4];
  __shared__ float ra[BLK / 64], rb[BLK / 64];
  const int b = blockIdx.x, t = threadIdx.x;
  const int lane = t & 63, wid = t >> 6;
  half2_t w[H2C];
  const half2_t* wp = Wp + t;
  #pragma unroll
  for (int j2 = 0; j2 < H2C; ++j2) w[j2] = wp[(size_t)j2 * H4];
  float cc = 0.f;
  if (t < H) hsh[t] = (_Float16)0.f;
  const float bval = bias[t];
  const size_t base = (size_t)b * S * H4 + t;
  float pv0[Z], pv1[Z];
  #pragma unroll
  for (int z = 0; z < Z; ++z) pv0[z] = P[(size_t)z * MN + base];
  #pragma unroll
  for (int z = 0; z < Z; ++z) pv1[z] = P[(size_t)z * MN + base + H4];
  __syncthreads();
  const half2_t* hp = reinterpret_cast<const half2_t*>(hsh);
  for (int s = 0; s < S; ++s){
    float pvn[Z];
    if (s + 2 < S){
      size_t o2 = base + (size_t)(s + 2) * H4;
      #pragma unroll
      for (int z = 0; z < Z; ++z) pvn[z] = P[(size_t)z * MN + o2];
    }
    float a0 = bval, a1 = 0.f, a2 = 0.f, a3 = 0.f;
    float a4 = 0.f, a5 = 0.f, a6 = 0.f, a7 = 0.f;
    #pragma unroll
    for (int z = 0; z < Z; ++z) a0 += pv0[z];
    #pragma unroll
    for (int j2 = 0; j2 < H2C; j2 += 8){
      a0 = dot2(w[j2],     hp[j2],     a0);
      a1 = dot2(w[j2 + 1], hp[j2 + 1], a1);
      a2 = dot2(w[j2 + 2], hp[j2 + 2], a2);
      a3 = dot2(w[j2 + 3], hp[j2 + 3], a3);
      a4 = dot2(w[j2 + 4], hp[j2 + 4], a4);
      a5 = dot2(w[j2 + 5], hp[j2 + 5], a5);
      a6 = dot2(w[j2 + 6], hp[j2 + 6], a6);
      a7 = dot2(w[j2 + 7], hp[j2 + 7], a7);
    }
    gv[t] = ((a0 + a1) + (a2 + a3)) + ((a4 + a5) + (a6 + a7));
    __syncthreads();
    float gvv = 0.f;
    if (t < H){
      float ig = sigf(gv[t]);
      float fg = sigf(gv[H + t]);
      float gg = tanhf(gv[2 * H + t]);
      float og = sigf(gv[3 * H + t]);
      cc = fg * cc + ig * gg;
      float hh = og * tanhf(cc);
      hsh[t] = (_Float16)hh;
      out[((size_t)b * S + s) * H + t] = hh;
      gvv = hh;
    }
    float q1 = gvv, q2 = gvv * gvv;
    for (int off2 = 32; off2; off2 >>= 1){ q1 += __shfl_down(q1, off2); q2 += __shfl_down(q2, off2); }
    if (lane == 0){ ra[wid] = q1; rb[wid] = q2; }
    __syncthreads();
    if (t == 0){
      float sa = 0.f, sb = 0.f;
      #pragma unroll
      for (int ww = 0; ww < BLK / 64; ++ww){ sa += ra[ww]; sb += rb[ww]; }
      atomicAdd(&ssum[s], sa);
      atomicAdd(&ssq[s], sb);
    }
    #pragma unroll
    for (int z = 0; z < Z; ++z){ pv0[z] = pv1[z]; pv1[z] = pvn[z]; }
  }
}

// ---------------- support2 with inline bnseg: A2mat[(nm*S+s)*25+v][k*96+c], stride 1280 ----------------
__global__ void support2_bn(const float* __restrict__ A, const float* __restrict__ lout,
                            const float* __restrict__ ssum, const float* __restrict__ ssq,
                            const float* __restrict__ g, const float* __restrict__ bb,
                            bf16_t* __restrict__ A2mat, int S, int cnt){
  int idx = blockIdx.x * blockDim.x + threadIdx.x;
  int total = 4 * S * 25 * 13 * 96;
  if (idx >= total) return;
  int c = idx % 96;
  int k = (idx / 96) % 13;
  int v = (idx / (96 * 13)) % 25;
  int rs = idx / (96 * 13 * 25);       // nm*S + s
  int s = rs % S, nm = rs / S;
  float mean = ssum[s] / cnt;
  float rstd = rsqrtf(ssq[s] / cnt - mean * mean + 1e-5f);
  float scale = rstd * g[s];
  float shift = bb[s] - mean * scale;
  const float* ar = A + (k * 25 + v) * 25;
  float acc = 0.f;
  #pragma unroll
  for (int u = 0; u < 25; ++u){
    float raw = lout[((size_t)(nm * 25 + u) * S + s) * 96 + c];
    acc += ar[u] * (raw * scale + shift);
  }
  A2mat[((size_t)rs * 25 + v) * 1280 + k * 96 + c] = f2bf(acc);
}

// ---------------- bnseg2 (from sums) + global pool ----------------
__global__ void pool_kernel(const float* __restrict__ lout2, const float* __restrict__ sum,
                            const float* __restrict__ sumsq, const float* __restrict__ g,
                            const float* __restrict__ bb, float* __restrict__ pooled,
                            int S, int H, int scnt){
  int n = blockIdx.x / H;
  int o = blockIdx.x % H;
  float acc = 0.f;
  int cnt = 2 * 25 * S;
  for (int i = threadIdx.x; i < cnt; i += 64){
    int m = i / (25 * S);
    int r = i % (25 * S);
    int v = r / S;
    int s = r % S;
    int b = (n * 2 + m) * 25 + v;
    float val = lout2[((size_t)b * S + s) * H + o];
    float mean = sum[s] / scnt;
    float rstd = rsqrtf(sumsq[s] / scnt - mean * mean + 1e-5f);
    val = (val - mean) * rstd * g[s] + bb[s];
    acc += val;
  }
  for (int off = 32; off; off >>= 1) acc += __shfl_down(acc, off);
  if (threadIdx.x == 0) pooled[n * H + o] = acc / cnt;
}

// ---------------- final FC ----------------
__global__ void fc_kernel(const float* __restrict__ pooled, const float* __restrict__ fcW,
                          const float* __restrict__ fcb, float* __restrict__ outp){
  int idx = blockIdx.x * blockDim.x + threadIdx.x;
  if (idx >= 120) return;
  int n = idx / 60, cls = idx % 60;
  float acc = fcb[cls];
  for (int o = 0; o < 192; ++o) acc += pooled[n * 192 + o] * fcW[cls * 192 + o];
  outp[idx] = acc;
}

// ---------------- host: replicate np.linspace + python round (ties-to-even) ----------------
static void make_segs(int T, int S, SegTable& tab, int& L){
  double step = (double)(T - 1) / (double)S;
  long long tv[51];
  for (int i = 0; i <= S; ++i){
    double v = 1.0 + step * (double)i;
    tv[i] = llrint(v);
  }
  L = 0;
  for (int s = 0; s < S; ++s){
    tab.st[s] = (int)tv[s] - 1;
    tab.en[s] = (int)tv[s + 1] - 1;
    int len = tab.en[s] - tab.st[s] + 1;
    if (len > L) L = len;
  }
  for (int s = S; s < 50; ++s){ tab.st[s] = 0; tab.en[s] = 0; }
  if (L > 4) L = 4;
}

extern "C" void kernel_launch(void* const* d_in, const int* in_sizes, int n_in,
                              void* d_out, int out_size, void* d_ws, size_t ws_size,
                              hipStream_t stream){
  const float* x         = (const float*)d_in[0];
  const float* data_bn_g = (const float*)d_in[2];
  const float* data_bn_b = (const float*)d_in[3];
  const float* A_powers1 = (const float*)d_in[4];
  const float* A_res1    = (const float*)d_in[5];
  const float* W1        = (const float*)d_in[6];
  const float* b1        = (const float*)d_in[7];
  const float* bn1_g     = (const float*)d_in[8];
  const float* bn1_b     = (const float*)d_in[9];
  const float* Wih1      = (const float*)d_in[10];
  const float* Whh1      = (const float*)d_in[11];
  const float* bih1      = (const float*)d_in[12];
  const float* bhh1      = (const float*)d_in[13];
  const float* bnseg1_g  = (const float*)d_in[14];
  const float* bnseg1_b  = (const float*)d_in[15];
  const float* A_powers2 = (const float*)d_in[16];
  const float* A_res2    = (const float*)d_in[17];
  const float* W2        = (const float*)d_in[18];
  const float* b2        = (const float*)d_in[19];
  const float* bn2_g     = (const float*)d_in[20];
  const float* bn2_b     = (const float*)d_in[21];
  const float* Wih2      = (const float*)d_in[22];
  const float* Whh2      = (const float*)d_in[23];
  const float* bih2      = (const float*)d_in[24];
  const float* bhh2      = (const float*)d_in[25];
  const float* bnseg2_g  = (const float*)d_in[26];
  const float* bnseg2_b  = (const float*)d_in[27];
  const float* fcW       = (const float*)d_in[28];
  const float* fcb       = (const float*)d_in[29];
  float* out = (float*)d_out;

  const int N = 2, C = 3, T = 100, V = 25, M = 2, NM = 4;
  const int C1 = 96, C2 = 192;
  const int S1 = 50, S2 = 30;
  const int B = 100;
  const int IN1 = 4752, IN2 = 18720;
  const int IN1P = 4800, IN2P = 18752;  // K padded to %64
  const int P1 = 4560, P2 = 18336;
  const int KG2 = 1248, KG2P = 1280;
  const int Z1 = 5, Z2 = 7, ZG = 4;     // Z2=7: 12x3x7 = 252 blocks = 1/CU for the 8-phase kernel

  size_t off = 0;
  char* base = (char*)d_ws;
  auto alloc = [&](size_t nbytes) -> void* {
    off = (off + 255) & ~(size_t)255;
    void* p = base + off;
    off += nbytes;
    return p;
  };
  float* A1full = (float*)alloc(325 * 25 * 4);
  float* A2full = (float*)alloc(325 * 25 * 4);
  float* h1     = (float*)alloc((size_t)NM * C * T * V * 4);
  float* y1mat  = (float*)alloc((size_t)NM * T * V * C1 * 4);
  float* stats  = (float*)alloc(736 * 4);
  float* st1a = stats, *st1b = stats + 96;
  float* sg1a = stats + 192, *sg1b = stats + 242;
  float* st2a = stats + 292, *st2b = stats + 484;
  float* sg2a = stats + 676, *sg2b = stats + 706;
  float* l1out  = (float*)alloc((size_t)B * S1 * C1 * 4);
  bf16_t* A2mat = (bf16_t*)alloc((size_t)NM * S1 * V * KG2P * 2);
  float* y2mat  = (float*)alloc((size_t)NM * S1 * V * C2 * 4);
  float* l2out  = (float*)alloc((size_t)B * S2 * C2 * 4);
  float* pooled = (float*)alloc(2 * C2 * 4);
  float* bias1  = (float*)alloc(4 * C1 * 4);
  float* bias2  = (float*)alloc(4 * C2 * 4);
  half2_t* Wp1  = (half2_t*)alloc((size_t)(C1 / 2) * 4 * C1 * 4);
  half2_t* Wp2  = (half2_t*)alloc((size_t)(C2 / 2) * 4 * C2 * 4);
  bf16_t* Wih1b = (bf16_t*)alloc((size_t)4 * C1 * IN1P * 2);
  bf16_t* Wih2b = (bf16_t*)alloc((size_t)4 * C2 * IN2P * 2);
  bf16_t* W2b   = (bf16_t*)alloc((size_t)C2 * KG2P * 2);
  unsigned short* lut1 = (unsigned short*)alloc((size_t)P1 * 2);
  unsigned short* lut2 = (unsigned short*)alloc((size_t)P2 * 2);
  size_t pmax = (size_t)Z2 * 3000 * 768;
  {
    size_t p1s = (size_t)Z1 * 5000 * 384; if (p1s > pmax) pmax = p1s;
    size_t pgs = (size_t)ZG * 5000 * 192; if (pgs > pmax) pmax = pgs;
  }
  float* Pbuf = (float*)alloc(pmax * 4);
  bf16_t* feats = (bf16_t*)alloc((size_t)B * S2 * IN2P * 2);
  (void)ws_size; (void)in_sizes; (void)n_in; (void)out_size;

  // 1) prep: adds, whh packs, LUTs, stat zeros, A2mat K-pad
  prep_misc<<<625, 256, 0, stream>>>(A_powers1, A_res1, A1full, A_powers2, A_res2, A2full,
                                     bih1, bhh1, bias1, bih2, bhh2, bias2,
                                     Whh1, Wp1, Whh2, Wp2, lut1, lut2, stats, A2mat);
  // 2) weight bf16 conversion (one dispatch)
  {
    int c1 = 4 * C1 * (IN1P / 8);
    int c2 = 4 * C2 * (IN2P / 8);
    int c3 = C2 * (KG2P / 8);
    int tot = c1 + c2 + c3;
    f2bf_pad8_3<<<(tot + 255) / 256, 256, 0, stream>>>(Wih1, Wih1b, IN1, IN1P, c1,
                                                       Wih2, Wih2b, IN2, IN2P, c2,
                                                       W2, W2b, KG2, KG2P, c3);
  }

  // 3) data BN
  data_bn_kernel<<<M * V * C, 64, 0, stream>>>(x, data_bn_g, data_bn_b, h1, N, C, T, V, M);

  // 4) GCN1 fused (support + contract + stats)
  gcn1_fused<<<NM * T, 256, 0, stream>>>(A1full, h1, W1, b1, y1mat, st1a, st1b, T);

  SegTable seg1, seg2; int L1, L2;
  make_segs(T, S1, seg1, L1);
  make_segs(S1, S2, seg2, L2);

  // 5) feats1 (bn+relu inline)
  feats_bn_kernel<<<B * S1, 256, 0, stream>>>(y1mat, st1a, st1b, bn1_g, bn1_b, feats, seg1,
                                              (const unsigned int*)lut1, T, C1, S1, L1, P1, IN1P,
                                              NM * T * 25);
  // 6) xp1 GEMM + 7) lstm1 (+segstats fused)
  {
    int Mm = B * S1, Nn = 4 * C1;
    int GX = (Mm + 127) / 128, GY = (Nn + 127) / 128;
    gemm_mfma_nt_split<<<GX * GY * Z1, 256, 0, stream>>>(feats, Wih1b, Pbuf, Mm, Nn, IN1P,
                                                         GX, GY, Z1);
    lstm_kernel<48, 384, Z1><<<B, 384, 0, stream>>>(Pbuf, bias1, Wp1, l1out, sg1a, sg1b, S1, Mm * Nn);
  }

  // 8) support2 (+bnseg inline)
  {
    int tot = NM * S1 * 25 * 13 * 96;
    support2_bn<<<(tot + 255) / 256, 256, 0, stream>>>(A2full, l1out, sg1a, sg1b, bnseg1_g,
                                                       bnseg1_b, A2mat, S1, B * C1);
  }
  // 9) GCN2 GEMM + 10) reduce+bias+colstats
  {
    int Mm = NM * S1 * 25, Nn = C2;
    int GX = (Mm + 127) / 128, GY = (Nn + 127) / 128;
    gemm_mfma_nt_split<<<GX * GY * ZG, 256, 0, stream>>>(A2mat, W2b, Pbuf, Mm, Nn, KG2P,
                                                         GX, GY, ZG);
    int MN = Mm * Nn;
    reduce_split_bias_stats<<<(MN / 4 + 255) / 256, 256, 0, stream>>>(Pbuf, b2, y2mat, st2a, st2b,
                                                                      MN, Nn, ZG);
  }

  // 11) feats2 (bn+relu inline)
  feats_bn_kernel<<<B * S2, 256, 0, stream>>>(y2mat, st2a, st2b, bn2_g, bn2_b, feats, seg2,
                                              (const unsigned int*)lut2, S1, C2, S2, L2, P2, IN2P,
                                              NM * S1 * 25);
  // 12) xp2 GEMM (256^2 8-phase, 1-barrier/phase, XCD-chunked) + 13) lstm2 (+segstats fused)
  {
    int Mm = B * S2, Nn = 4 * C2;     // 3000 x 768, K = 18752 (293 K-steps)
    int GX = (Mm + 255) / 256, GY = (Nn + 255) / 256;   // 12 x 3 x 7 = 252 blocks
    gemm_mfma_nt_8ph<<<GX * GY * Z2, 512, 0, stream>>>(feats, Wih2b, Pbuf, Mm, Nn, IN2P,
                                                       GX, GY, Z2);
    lstm_kernel<96, 768, Z2><<<B, 768, 0, stream>>>(Pbuf, bias2, Wp2, l2out, sg2a, sg2b, S2, Mm * Nn);
  }

  // 14) pool, 15) fc
  pool_kernel<<<2 * C2, 64, 0, stream>>>(l2out, sg2a, sg2b, bnseg2_g, bnseg2_b, pooled, S2, C2, B * C2);
  fc_kernel<<<1, 128, 0, stream>>>(pooled, fcW, fcb, out);
}

// Round 8
// 622.618 us; speedup vs baseline: 1.0721x; 1.0587x over previous
//
#include <hip/hip_runtime.h>
#include <cmath>
#include <cstdint>
#include <cstddef>

typedef unsigned short bf16_t;
typedef __attribute__((ext_vector_type(8))) short short8;
typedef __attribute__((ext_vector_type(4))) float floatx4;
typedef __attribute__((ext_vector_type(2))) _Float16 half2_t;

__device__ __forceinline__ float bf2f(bf16_t b){
  unsigned int u = ((unsigned int)b) << 16;
  return __uint_as_float(u);
}
__device__ __forceinline__ bf16_t f2bf(float f){
  unsigned int u = __float_as_uint(f);
  unsigned int r = (u + 0x7fffu + ((u >> 16) & 1u)) >> 16;  // RNE
  return (bf16_t)r;
}
__device__ __forceinline__ unsigned int f2bf2(float a, float b){
  return (unsigned int)f2bf(a) | ((unsigned int)f2bf(b) << 16);
}
__device__ __forceinline__ float sigf(float x){ return 1.0f / (1.0f + expf(-x)); }

__device__ __forceinline__ float dot2(half2_t a, half2_t b, float c){
#if __has_builtin(__builtin_amdgcn_fdot2)
  return __builtin_amdgcn_fdot2(a, b, c, false);
#else
  return c + (float)a.x * (float)b.x + (float)a.y * (float)b.y;
#endif
}

__device__ __forceinline__ void gload_lds16(const bf16_t* g, bf16_t* lds){
  __builtin_amdgcn_global_load_lds(
      (const __attribute__((address_space(1))) unsigned int*)g,
      (__attribute__((address_space(3))) unsigned int*)lds, 16, 0, 0);
}

__device__ __forceinline__ void barrier_raw(){
  asm volatile("s_barrier" ::: "memory");
}

// XCD-chunked bijective swizzle (T1, m204 variant). MI355X dispatch round-robins
// blocks across 8 XCDs (XCD = dispatch_id % 8). Remap so each XCD executes a
// CONTIGUOUS logical chunk -> co-XCD blocks share A/B panels and hit in L2.
__device__ __forceinline__ int xcd_chunk_swizzle(int orig, int nwg){
  int q = nwg >> 3, r = nwg & 7;
  int xcd = orig & 7, idx = orig >> 3;
  return (xcd < r ? xcd * (q + 1) : r * (q + 1) + (xcd - r) * q) + idx;
}

// ---------------- mega prep kernel: adds, whh pack, LUTs, stat zero, A2mat K-pad ----------------
__global__ void prep_misc(const float* __restrict__ a1, const float* __restrict__ r1, float* __restrict__ o1,
                          const float* __restrict__ a2, const float* __restrict__ r2, float* __restrict__ o2,
                          const float* __restrict__ bi1, const float* __restrict__ bh1, float* __restrict__ ob1,
                          const float* __restrict__ bi2, const float* __restrict__ bh2, float* __restrict__ ob2,
                          const float* __restrict__ Whh1, half2_t* __restrict__ Wp1,
                          const float* __restrict__ Whh2, half2_t* __restrict__ Wp2,
                          unsigned short* __restrict__ lut1, unsigned short* __restrict__ lut2,
                          float* __restrict__ stats, bf16_t* __restrict__ A2mat){
  int i = blockIdx.x * blockDim.x + threadIdx.x;
  if (i < 8125){ o1[i] = a1[i] + r1[i]; o2[i] = a2[i] + r2[i]; }
  if (i < 384) ob1[i] = bi1[i] + bh1[i];
  if (i < 768) ob2[i] = bi2[i] + bh2[i];
  if (i < 736) stats[i] = 0.f;
  if (i < 18432){                       // pack Whh1 (H=96): Wp[j2*384+t]
    int t = i % 384, j2 = i / 384;
    half2_t w; w.x = (_Float16)Whh1[(size_t)t * 96 + 2 * j2];
    w.y = (_Float16)Whh1[(size_t)t * 96 + 2 * j2 + 1];
    Wp1[i] = w;
  }
  if (i < 73728){                       // pack Whh2 (H=192)
    int t = i % 768, j2 = i / 768;
    half2_t w; w.x = (_Float16)Whh2[(size_t)t * 192 + 2 * j2];
    w.y = (_Float16)Whh2[(size_t)t * 192 + 2 * j2 + 1];
    Wp2[i] = w;
  }
  // levy pair LUTs: flat p -> (i<<8)|j
  if (i < 4560){
    int d = 96, p = i;
    int r = (int)(((2.0 * d - 1.0) - sqrt((2.0 * d - 1.0) * (2.0 * d - 1.0) - 8.0 * (double)p)) * 0.5);
    if (r < 0) r = 0;
    while (r + 1 <= d - 2 && (r + 1) * (d - 1) - ((r + 1) * r) / 2 <= p) ++r;
    while (r > 0 && r * (d - 1) - (r * (r - 1)) / 2 > p) --r;
    int jj = p - (r * (d - 1) - (r * (r - 1)) / 2);
    lut1[p] = (unsigned short)((r << 8) | (r + 1 + jj));
  }
  if (i < 18336){
    int d = 192, p = i;
    int r = (int)(((2.0 * d - 1.0) - sqrt((2.0 * d - 1.0) * (2.0 * d - 1.0) - 8.0 * (double)p)) * 0.5);
    if (r < 0) r = 0;
    while (r + 1 <= d - 2 && (r + 1) * (d - 1) - ((r + 1) * r) / 2 <= p) ++r;
    while (r > 0 && r * (d - 1) - (r * (r - 1)) / 2 > p) --r;
    int jj = p - (r * (d - 1) - (r * (r - 1)) / 2);
    lut2[p] = (unsigned short)((r << 8) | (r + 1 + jj));
  }
  if (i < 160000){                      // A2mat K-pad cols [1248,1280), 5000 rows
    int row = i >> 5, col = 1248 + (i & 31);
    A2mat[(size_t)row * 1280 + col] = 0;
  }
}

// ---------------- three fp32->bf16 pad conversions in ONE dispatch ----------------
__device__ __forceinline__ void f2bf_seg(const float* in, bf16_t* out, int Kin, int Kout, int li){
  int ko8 = Kout >> 3;
  int r = li / ko8, k8 = (li % ko8) << 3;
  uint4 u;
  if (k8 + 8 <= Kin){
    const float4* p = reinterpret_cast<const float4*>(in + (size_t)r * Kin + k8);
    float4 x0 = p[0], x1 = p[1];
    u.x = f2bf2(x0.x, x0.y); u.y = f2bf2(x0.z, x0.w);
    u.z = f2bf2(x1.x, x1.y); u.w = f2bf2(x1.z, x1.w);
  } else {
    u.x = u.y = u.z = u.w = 0u;
  }
  *reinterpret_cast<uint4*>(out + (size_t)r * Kout + k8) = u;
}

__global__ void f2bf_pad8_3(const float* __restrict__ in1, bf16_t* __restrict__ out1, int Kin1, int Kout1, int c1,
                            const float* __restrict__ in2, bf16_t* __restrict__ out2, int Kin2, int Kout2, int c2,
                            const float* __restrict__ in3, bf16_t* __restrict__ out3, int Kin3, int Kout3, int c3){
  int idx = blockIdx.x * blockDim.x + threadIdx.x;
  if (idx < c1){ f2bf_seg(in1, out1, Kin1, Kout1, idx); return; }
  idx -= c1;
  if (idx < c2){ f2bf_seg(in2, out2, Kin2, Kout2, idx); return; }
  idx -= c2;
  if (idx < c3) f2bf_seg(in3, out3, Kin3, Kout3, idx);
}

// ---------------- data batchnorm: x(N,C,T,V,M) -> h1[(nm*C+c)*T+t][V] ----------------
__global__ void data_bn_kernel(const float* __restrict__ x, const float* __restrict__ g,
                               const float* __restrict__ bb, float* __restrict__ h1,
                               int N, int C, int T, int V, int M){
  int ch = blockIdx.x;             // (m*V + v)*C + c
  int m = ch / (V * C);
  int v = (ch / C) % V;
  int c = ch % C;
  int tid = threadIdx.x;
  int cnt = N * T;
  float s = 0.f, s2 = 0.f;
  for (int i = tid; i < cnt; i += 64){
    int n = i / T, t = i % T;
    float val = x[(((size_t)(n * C + c) * T + t) * V + v) * M + m];
    s += val; s2 += val * val;
  }
  for (int off = 32; off; off >>= 1){ s += __shfl_down(s, off); s2 += __shfl_down(s2, off); }
  s = __shfl(s, 0); s2 = __shfl(s2, 0);
  float mean = s / cnt;
  float rstd = rsqrtf(s2 / cnt - mean * mean + 1e-5f);
  float gg = g[ch], bo = bb[ch];
  for (int i = tid; i < cnt; i += 64){
    int n = i / T, t = i % T;
    float val = x[(((size_t)(n * C + c) * T + t) * V + v) * M + m];
    float y = (val - mean) * rstd * gg + bo;
    h1[((size_t)((n * M + m) * C + c) * T + t) * V + v] = y;
  }
}

// ---------------- GCN1 fused: support + W-contract + colstats. block = (nm,t) ----------------
__global__ __launch_bounds__(256)
void gcn1_fused(const float* __restrict__ A, const float* __restrict__ h1,
                const float* __restrict__ W1, const float* __restrict__ b1,
                float* __restrict__ y1, float* __restrict__ ssum, float* __restrict__ ssq, int T){
  __shared__ float h[3][25];
  __shared__ float sup[3][325];
  __shared__ float lsum[96], lsq[96];
  int blk = blockIdx.x;
  int nm = blk / T, t = blk % T;
  int tid = threadIdx.x;
  if (tid < 75){
    int c = tid / 25, v = tid % 25;
    h[c][v] = h1[((size_t)(nm * 3 + c) * T + t) * 25 + v];
  }
  if (tid < 96){ lsum[tid] = 0.f; lsq[tid] = 0.f; }
  __syncthreads();
  for (int w = tid; w < 975; w += 256){
    int c = w / 325, ww = w % 325;
    const float* ar = A + ww * 25;
    float acc = 0.f;
    #pragma unroll
    for (int u = 0; u < 25; ++u) acc += ar[u] * h[c][u];
    sup[c][ww] = acc;
  }
  __syncthreads();
  for (int o2 = tid; o2 < 2400; o2 += 256){
    int v = o2 / 96, o = o2 % 96;
    float acc = b1[o];
    #pragma unroll
    for (int k = 0; k < 13; ++k)
      #pragma unroll
      for (int c = 0; c < 3; ++c)
        acc += W1[o * 39 + k * 3 + c] * sup[c][k * 25 + v];
    y1[((size_t)blk * 25 + v) * 96 + o] = acc;
    atomicAdd(&lsum[o], acc);
    atomicAdd(&lsq[o], acc * acc);
  }
  __syncthreads();
  if (tid < 96){ atomicAdd(&ssum[tid], lsum[tid]); atomicAdd(&ssq[tid], lsq[tid]); }
}

// ---------------- feats with inline BN+relu: reads y-mat + stats, writes bf16 rows ----------------
struct SegTable { int st[50]; int en[50]; };

__global__ void feats_bn_kernel(const float* __restrict__ ymat, const float* __restrict__ sum,
                                const float* __restrict__ sumsq, const float* __restrict__ g,
                                const float* __restrict__ bb, bf16_t* __restrict__ feats,
                                SegTable segs, const unsigned int* __restrict__ lut32,
                                int T, int d, int S, int L, int pairs, int rowlenP, int R){
  __shared__ float pts[4][192];
  int bs = blockIdx.x;
  int b = bs / S, s = bs % S;
  int nm = b / 25, v = b % 25;
  int st = segs.st[s], en = segs.en[s];
  int nt = blockDim.x, tid = threadIdx.x;
  for (int l = 0; l < L; ++l){
    int t = st + l; if (t > en) t = en;
    const float* yrow = ymat + ((size_t)(nm * T + t) * 25 + v) * d;
    for (int i = tid; i < d; i += nt){
      float mean = sum[i] / R;
      float rstd = rsqrtf(sumsq[i] / R - mean * mean + 1e-5f);
      pts[l][i] = fmaxf((yrow[i] - mean) * rstd * g[i] + bb[i], 0.f);
    }
  }
  __syncthreads();
  unsigned int* frow32 = reinterpret_cast<unsigned int*>(feats + (size_t)bs * rowlenP);
  int d2 = d >> 1;
  for (int i2 = tid; i2 < d2; i2 += nt){
    int i = 2 * i2;
    frow32[i2]      = f2bf2(pts[0][i], pts[0][i + 1]);
    frow32[d2 + i2] = f2bf2(pts[L - 1][i] - pts[0][i], pts[L - 1][i + 1] - pts[0][i + 1]);
  }
  int rowlen2 = (2 * d + pairs) >> 1, rowlenP2 = rowlenP >> 1;
  for (int i = tid + rowlen2; i < rowlenP2; i += nt) frow32[i] = 0;  // K pad
  int Lm2 = L - 2;
  unsigned int* lrow32 = frow32 + d;
  int pairs2 = pairs >> 1;
  for (int p2 = tid; p2 < pairs2; p2 += nt){
    unsigned int ee = lut32[p2];
    int i0 = (ee >> 8) & 255, j0 = ee & 255;
    int i1 = ee >> 24, j1 = (ee >> 16) & 255;
    float acc0 = 0.f, acc1 = 0.f;
    for (int l = 1; l <= Lm2; ++l){
      float ri = pts[l][i0] - pts[0][i0], rj = pts[l][j0] - pts[0][j0];
      float di = pts[l + 1][i0] - pts[l][i0], dj = pts[l + 1][j0] - pts[l][j0];
      acc0 += ri * dj - rj * di;
      float ri1 = pts[l][i1] - pts[0][i1], rj1 = pts[l][j1] - pts[0][j1];
      float di1 = pts[l + 1][i1] - pts[l][i1], dj1 = pts[l + 1][j1] - pts[l][j1];
      acc1 += ri1 * dj1 - rj1 * di1;
    }
    lrow32[p2] = f2bf2(0.5f * acc0, 0.5f * acc1);
  }
}

// ---------------- split-K MFMA bf16 NT GEMM, BK=64, XOR-swizzled LDS (128x128, 2-phase) ----------------
// Launched 1-D with flat grid GX*GY*GZ; XCD-chunk swizzled inside (T1). Used by GCN2 only.
__global__ __launch_bounds__(256)
void gemm_mfma_nt_split(const bf16_t* __restrict__ A, const bf16_t* __restrict__ B,
                        float* __restrict__ P, int M, int N, int K,
                        int GX, int GY, int GZ){
  __shared__ bf16_t As[128 * 64];
  __shared__ bf16_t Bs[128 * 64];
  const int nwg = GX * GY * GZ;
  const int wg = xcd_chunk_swizzle(blockIdx.x, nwg);
  const int bxi = wg % GX, byi = (wg / GX) % GY, bzi = wg / (GX * GY);
  const int tid = threadIdx.x;
  const int lane = tid & 63, wv = tid >> 6;
  const int bm = bxi * 128, bn = byi * 128;
  const int wr = (wv >> 1) * 64, wc = (wv & 1) * 64;
  const int m_l = lane & 15, q = lane >> 4;

  const int ksteps = K >> 6;
  const int Z = GZ, z = bzi;
  const int per = (ksteps + Z - 1) / Z;
  const int ks0 = z * per;
  const int ks1 = (ks0 + per < ksteps) ? ks0 + per : ksteps;

  const int rlane = lane >> 3;
  const int slane = lane & 7;
  const int colc = (slane ^ rlane) * 8;
  const bf16_t* gA[4]; const bf16_t* gB[4];
  bf16_t* lA[4]; bf16_t* lB[4];
  #pragma unroll
  for (int it = 0; it < 4; ++it){
    int c = it * 4 + wv;
    int rowA = bm + c * 8 + rlane; if (rowA > M - 1) rowA = M - 1;
    int rowB = bn + c * 8 + rlane; if (rowB > N - 1) rowB = N - 1;
    gA[it] = A + (size_t)rowA * K + colc;
    gB[it] = B + (size_t)rowB * K + colc;
    lA[it] = &As[c * 512];
    lB[it] = &Bs[c * 512];
  }
  const int sxor = m_l & 7;

  floatx4 acc[4][4] = {};
  for (int ks = ks0; ks < ks1; ++ks){
    int k0 = ks << 6;
    __syncthreads();
    #pragma unroll
    for (int it = 0; it < 4; ++it){
      gload_lds16(gA[it] + k0, lA[it]);
      gload_lds16(gB[it] + k0, lB[it]);
    }
    __syncthreads();
    #pragma unroll
    for (int half = 0; half < 2; ++half){
      const int scol = ((half * 4 + q) ^ sxor) * 8;
      short8 af[4], bfr[4];
      #pragma unroll
      for (int i = 0; i < 4; ++i){
        af[i]  = *reinterpret_cast<const short8*>(&As[(wr + i * 16 + m_l) * 64 + scol]);
        bfr[i] = *reinterpret_cast<const short8*>(&Bs[(wc + i * 16 + m_l) * 64 + scol]);
      }
      #pragma unroll
      for (int mi = 0; mi < 4; ++mi)
        #pragma unroll
        for (int ni = 0; ni < 4; ++ni)
          acc[mi][ni] = __builtin_amdgcn_mfma_f32_16x16x32_bf16(af[mi], bfr[ni], acc[mi][ni], 0, 0, 0);
    }
  }

  float* Pz = P + (size_t)z * M * N;
  #pragma unroll
  for (int mi = 0; mi < 4; ++mi){
    int row0 = bm + wr + mi * 16 + q * 4;
    #pragma unroll
    for (int r = 0; r < 4; ++r){
      int row = row0 + r;
      if (row < M){
        #pragma unroll
        for (int ni = 0; ni < 4; ++ni){
          int col = bn + wc + ni * 16 + m_l;
          if (col < N) Pz[(size_t)row * N + col] = acc[mi][ni][r];
        }
      }
    }
  }
}

// ---------------- 256x256 2-half-phase counted-vmcnt split-K NT GEMM (T1+T2+T3+T4+T5) ----------------
// 512 thr = 8 waves (2M x 4N). LDS 128 KiB: As/Bs = [buf2][kh2][256 rows][32 cols] bf16 planes.
// r8 change vs r7: MERGED phases -> 2 half-phases/tile (was 4). Each HP: read ALL 8 A-frags +
// 4 B-frags (12 x ds_read_b128), stage next plane-pair (4 gloads), counted vmcnt, ONE barrier,
// 32 MFMA. Halves per-tile fixed overhead (2 barriers+2 vmcnt, was 4+4 in r4, 8 in r2-r4).
// VGPR: af[8]+bfr[4]+acc[8][4] ~ 200 < 256 budget of 2 waves/SIMD (LDS caps at 1 block/CU anyway).
// Ledger (4 loads per STG4): steady O=4..8; HP(kh0)'s VMC4 drains this tile's kh1 (read next HP);
// HP(kh1)'s VMC4 drains next tile's kh0. Epilogue: VMC0 in kh0's wait slot drains kh1.
// Read guards: HP(X) reads are covered by HP(X-1)'s wait+barrier. WAR: a wave crosses a barrier
// only after its MFMA (lgkmcnt-retired reads) of the prior HP; stages into a plane occur >=2
// barriers after its last reads. Same proven order as r4/r7: reads -> stage -> wait -> bar -> MFMA.
#define VMC4 asm volatile("s_waitcnt vmcnt(4)" ::: "memory")
#define VMC0 asm volatile("s_waitcnt vmcnt(0)" ::: "memory")
#define STG4(NB, KH, OFF) { gload_lds16(pA0 + (OFF) + (KH) * 32, dA0 + (NB) * 16384 + (KH) * 8192); \
                            gload_lds16(pA1 + (OFF) + (KH) * 32, dA1 + (NB) * 16384 + (KH) * 8192); \
                            gload_lds16(pB0 + (OFF) + (KH) * 32, dB0 + (NB) * 16384 + (KH) * 8192); \
                            gload_lds16(pB1 + (OFF) + (KH) * 32, dB1 + (NB) * 16384 + (KH) * 8192); }
#define HP(BUF, KH, STAGE_BLOCK, WAIT_BLOCK) { \
    const bf16_t* ab_ = As + (BUF) * 16384 + (KH) * 8192 + sA; \
    _Pragma("unroll") \
    for (int i_ = 0; i_ < 8; ++i_) af[i_] = *reinterpret_cast<const short8*>(ab_ + i_ * 512); \
    const bf16_t* bb_ = Bs + (BUF) * 16384 + (KH) * 8192 + sB; \
    _Pragma("unroll") \
    for (int i_ = 0; i_ < 4; ++i_) bfr[i_] = *reinterpret_cast<const short8*>(bb_ + i_ * 512); \
    STAGE_BLOCK; \
    WAIT_BLOCK; \
    barrier_raw(); \
    __builtin_amdgcn_s_setprio(1); \
    _Pragma("unroll") \
    for (int mi_ = 0; mi_ < 8; ++mi_) \
      _Pragma("unroll") \
      for (int ni_ = 0; ni_ < 4; ++ni_) \
        acc[mi_][ni_] = __builtin_amdgcn_mfma_f32_16x16x32_bf16(af[mi_], bfr[ni_], acc[mi_][ni_], 0, 0, 0); \
    __builtin_amdgcn_s_setprio(0); \
  }

__global__ __launch_bounds__(512, 2)
void gemm_mfma_nt_8ph(const bf16_t* __restrict__ A, const bf16_t* __restrict__ B,
                      float* __restrict__ P, int M, int N, int K,
                      int GX, int GY, int GZ){
  __shared__ bf16_t As[32768];   // 64 KiB: [2][2][256][32]
  __shared__ bf16_t Bs[32768];   // 64 KiB
  const int nwg = GX * GY * GZ;
  const int wg = xcd_chunk_swizzle(blockIdx.x, nwg);
  const int bxi = wg % GX, byi = (wg / GX) % GY, bzi = wg / (GX * GY);
  const int tid = threadIdx.x;
  const int lane = tid & 63, wv = tid >> 6;
  const int wm = wv >> 2, wn = wv & 3;
  const int m_l = lane & 15, q = lane >> 4;
  const int bm = bxi * 256, bn = byi * 256;

  const int ksteps = K >> 6;
  const int z = bzi, Z = GZ;
  const int per = (ksteps + Z - 1) / Z;
  const int ks0 = z * per;
  int ks1 = ks0 + per; if (ks1 > ksteps) ks1 = ksteps;
  if (ks0 >= ks1) return;

  // ---- staging addresses (swizzled global source, linear LDS dest) ----
  const int rlane = lane >> 2, slane = lane & 3;
  const int cg = slane ^ ((rlane >> 1) & 3);
  int rr0 = wv * 16 + rlane, rr1 = (8 + wv) * 16 + rlane;
  int ra0 = bm + rr0; if (ra0 > M - 1) ra0 = M - 1;
  int ra1 = bm + rr1; if (ra1 > M - 1) ra1 = M - 1;
  int rb0 = bn + rr0; if (rb0 > N - 1) rb0 = N - 1;
  int rb1 = bn + rr1; if (rb1 > N - 1) rb1 = N - 1;
  const bf16_t* pA0 = A + (size_t)ra0 * K + cg * 8 + ks0 * 64;
  const bf16_t* pA1 = A + (size_t)ra1 * K + cg * 8 + ks0 * 64;
  const bf16_t* pB0 = B + (size_t)rb0 * K + cg * 8 + ks0 * 64;
  const bf16_t* pB1 = B + (size_t)rb1 * K + cg * 8 + ks0 * 64;
  bf16_t* dA0 = As + wv * 512;
  bf16_t* dA1 = As + (8 + wv) * 512;
  bf16_t* dB0 = Bs + wv * 512;
  bf16_t* dB1 = Bs + (8 + wv) * 512;

  // ---- read base offsets (elems): row stride 32, XOR slot = q ^ ((m_l>>1)&3) ----
  const int sA = (wm * 128 + m_l) * 32 + ((q ^ ((m_l >> 1) & 3)) * 8);
  const int sB = (wn * 64 + m_l) * 32 + ((q ^ ((m_l >> 1) & 3)) * 8);

  short8 af[8], bfr[4];
  floatx4 acc[8][4] = {};

  // ---- prologue: stage tile ks0 into buf0 (kh0 then kh1) ----
  STG4(0, 0, 0); STG4(0, 1, 0);
  VMC4;            // kh0 landed; kh1 (4 loads) stays in flight
  barrier_raw();

  int buf = 0;
  for (int t = ks0; t < ks1 - 1; ++t){
    const int nb = buf ^ 1;
    // hp1: compute kh0 (all 8 mi); stage next tile kh0; vmcnt(4) -> this tile's kh1 landed
    HP(buf, 0, STG4(nb, 0, 64), VMC4);
    // hp2: compute kh1; stage next tile kh1; vmcnt(4) -> next tile's kh0 landed
    HP(buf, 1, STG4(nb, 1, 64), VMC4);
    pA0 += 64; pA1 += 64; pB0 += 64; pB1 += 64;
    buf = nb;
  }
  // ---- epilogue tile (no stages): VMC0 in kh0's wait slot drains kh1 ----
  HP(buf, 0, ((void)0), VMC0);
  HP(buf, 1, ((void)0), ((void)0));

  // ---- store ----
  float* Pz = P + (size_t)z * M * N;
  #pragma unroll
  for (int mi = 0; mi < 8; ++mi){
    int row0 = bm + wm * 128 + mi * 16 + q * 4;
    #pragma unroll
    for (int r = 0; r < 4; ++r){
      int row = row0 + r;
      if (row < M){
        #pragma unroll
        for (int ni = 0; ni < 4; ++ni){
          int col = bn + wn * 64 + ni * 16 + m_l;
          if (col < N) Pz[(size_t)row * N + col] = acc[mi][ni][r];
        }
      }
    }
  }
}

// ---------------- reduce split partials + bias + colstats (GCN2 path, N=192) ----------------
__global__ __launch_bounds__(256)
void reduce_split_bias_stats(const float* __restrict__ P, const float* __restrict__ bias,
                             float* __restrict__ out, float* __restrict__ ssum, float* __restrict__ ssq,
                             int MN, int N, int Z){
  __shared__ float lsum[192], lsq[192];
  int tid = threadIdx.x;
  if (tid < 192){ lsum[tid] = 0.f; lsq[tid] = 0.f; }
  __syncthreads();
  int i4 = (blockIdx.x * blockDim.x + tid) * 4;
  if (i4 < MN){
    const float4 bv = *reinterpret_cast<const float4*>(bias + (i4 % N));
    float4 s = bv;
    for (int z = 0; z < Z; ++z){
      const float4 p = *reinterpret_cast<const float4*>(P + (size_t)z * MN + i4);
      s.x += p.x; s.y += p.y; s.z += p.z; s.w += p.w;
    }
    *reinterpret_cast<float4*>(out + i4) = s;
    int c0 = i4 % N;
    atomicAdd(&lsum[c0],     s.x); atomicAdd(&lsq[c0],     s.x * s.x);
    atomicAdd(&lsum[c0 + 1], s.y); atomicAdd(&lsq[c0 + 1], s.y * s.y);
    atomicAdd(&lsum[c0 + 2], s.z); atomicAdd(&lsq[c0 + 2], s.z * s.z);
    atomicAdd(&lsum[c0 + 3], s.w); atomicAdd(&lsq[c0 + 3], s.w * s.w);
  }
  __syncthreads();
  if (tid < 192){ atomicAdd(&ssum[tid], lsum[tid]); atomicAdd(&ssq[tid], lsq[tid]); }
}

// ---------------- persistent LSTM: reg f16 weights, fused split-K reduce + segstats, P prefetch ----------------
template <int H2C, int BLK, int Z>
__global__ __launch_bounds__(BLK)
void lstm_kernel(const float* __restrict__ P, const float* __restrict__ bias,
                 const half2_t* __restrict__ Wp, float* __restrict__ out,
                 float* __restrict__ ssum, float* __restrict__ ssq,
                 int S, int MN){
  constexpr int H = 2 * H2C;
  constexpr int H4 = 4 * H;
  __shared__ _Float16 __attribute__((aligned(16))) hsh[H];
  __shared__ float gv[H4];
  __shared__ float ra[BLK / 64], rb[BLK / 64];
  const int b = blockIdx.x, t = threadIdx.x;
  const int lane = t & 63, wid = t >> 6;
  half2_t w[H2C];
  const half2_t* wp = Wp + t;
  #pragma unroll
  for (int j2 = 0; j2 < H2C; ++j2) w[j2] = wp[(size_t)j2 * H4];
  float cc = 0.f;
  if (t < H) hsh[t] = (_Float16)0.f;
  const float bval = bias[t];
  const size_t base = (size_t)b * S * H4 + t;
  float pv0[Z], pv1[Z];
  #pragma unroll
  for (int z = 0; z < Z; ++z) pv0[z] = P[(size_t)z * MN + base];
  #pragma unroll
  for (int z = 0; z < Z; ++z) pv1[z] = P[(size_t)z * MN + base + H4];
  __syncthreads();
  const half2_t* hp = reinterpret_cast<const half2_t*>(hsh);
  for (int s = 0; s < S; ++s){
    float pvn[Z];
    if (s + 2 < S){
      size_t o2 = base + (size_t)(s + 2) * H4;
      #pragma unroll
      for (int z = 0; z < Z; ++z) pvn[z] = P[(size_t)z * MN + o2];
    }
    float a0 = bval, a1 = 0.f, a2 = 0.f, a3 = 0.f;
    float a4 = 0.f, a5 = 0.f, a6 = 0.f, a7 = 0.f;
    #pragma unroll
    for (int z = 0; z < Z; ++z) a0 += pv0[z];
    #pragma unroll
    for (int j2 = 0; j2 < H2C; j2 += 8){
      a0 = dot2(w[j2],     hp[j2],     a0);
      a1 = dot2(w[j2 + 1], hp[j2 + 1], a1);
      a2 = dot2(w[j2 + 2], hp[j2 + 2], a2);
      a3 = dot2(w[j2 + 3], hp[j2 + 3], a3);
      a4 = dot2(w[j2 + 4], hp[j2 + 4], a4);
      a5 = dot2(w[j2 + 5], hp[j2 + 5], a5);
      a6 = dot2(w[j2 + 6], hp[j2 + 6], a6);
      a7 = dot2(w[j2 + 7], hp[j2 + 7], a7);
    }
    gv[t] = ((a0 + a1) + (a2 + a3)) + ((a4 + a5) + (a6 + a7));
    __syncthreads();
    float gvv = 0.f;
    if (t < H){
      float ig = sigf(gv[t]);
      float fg = sigf(gv[H + t]);
      float gg = tanhf(gv[2 * H + t]);
      float og = sigf(gv[3 * H + t]);
      cc = fg * cc + ig * gg;
      float hh = og * tanhf(cc);
      hsh[t] = (_Float16)hh;
      out[((size_t)b * S + s) * H + t] = hh;
      gvv = hh;
    }
    float q1 = gvv, q2 = gvv * gvv;
    for (int off2 = 32; off2; off2 >>= 1){ q1 += __shfl_down(q1, off2); q2 += __shfl_down(q2, off2); }
    if (lane == 0){ ra[wid] = q1; rb[wid] = q2; }
    __syncthreads();
    if (t == 0){
      float sa = 0.f, sb = 0.f;
      #pragma unroll
      for (int ww = 0; ww < BLK / 64; ++ww){ sa += ra[ww]; sb += rb[ww]; }
      atomicAdd(&ssum[s], sa);
      atomicAdd(&ssq[s], sb);
    }
    #pragma unroll
    for (int z = 0; z < Z; ++z){ pv0[z] = pv1[z]; pv1[z] = pvn[z]; }
  }
}

// ---------------- support2 with inline bnseg: A2mat[(nm*S+s)*25+v][k*96+c], stride 1280 ----------------
__global__ void support2_bn(const float* __restrict__ A, const float* __restrict__ lout,
                            const float* __restrict__ ssum, const float* __restrict__ ssq,
                            const float* __restrict__ g, const float* __restrict__ bb,
                            bf16_t* __restrict__ A2mat, int S, int cnt){
  int idx = blockIdx.x * blockDim.x + threadIdx.x;
  int total = 4 * S * 25 * 13 * 96;
  if (idx >= total) return;
  int c = idx % 96;
  int k = (idx / 96) % 13;
  int v = (idx / (96 * 13)) % 25;
  int rs = idx / (96 * 13 * 25);       // nm*S + s
  int s = rs % S, nm = rs / S;
  float mean = ssum[s] / cnt;
  float rstd = rsqrtf(ssq[s] / cnt - mean * mean + 1e-5f);
  float scale = rstd * g[s];
  float shift = bb[s] - mean * scale;
  const float* ar = A + (k * 25 + v) * 25;
  float acc = 0.f;
  #pragma unroll
  for (int u = 0; u < 25; ++u){
    float raw = lout[((size_t)(nm * 25 + u) * S + s) * 96 + c];
    acc += ar[u] * (raw * scale + shift);
  }
  A2mat[((size_t)rs * 25 + v) * 1280 + k * 96 + c] = f2bf(acc);
}

// ---------------- bnseg2 (from sums) + global pool ----------------
__global__ void pool_kernel(const float* __restrict__ lout2, const float* __restrict__ sum,
                            const float* __restrict__ sumsq, const float* __restrict__ g,
                            const float* __restrict__ bb, float* __restrict__ pooled,
                            int S, int H, int scnt){
  int n = blockIdx.x / H;
  int o = blockIdx.x % H;
  float acc = 0.f;
  int cnt = 2 * 25 * S;
  for (int i = threadIdx.x; i < cnt; i += 64){
    int m = i / (25 * S);
    int r = i % (25 * S);
    int v = r / S;
    int s = r % S;
    int b = (n * 2 + m) * 25 + v;
    float val = lout2[((size_t)b * S + s) * H + o];
    float mean = sum[s] / scnt;
    float rstd = rsqrtf(sumsq[s] / scnt - mean * mean + 1e-5f);
    val = (val - mean) * rstd * g[s] + bb[s];
    acc += val;
  }
  for (int off = 32; off; off >>= 1) acc += __shfl_down(acc, off);
  if (threadIdx.x == 0) pooled[n * H + o] = acc / cnt;
}

// ---------------- final FC ----------------
__global__ void fc_kernel(const float* __restrict__ pooled, const float* __restrict__ fcW,
                          const float* __restrict__ fcb, float* __restrict__ outp){
  int idx = blockIdx.x * blockDim.x + threadIdx.x;
  if (idx >= 120) return;
  int n = idx / 60, cls = idx % 60;
  float acc = fcb[cls];
  for (int o = 0; o < 192; ++o) acc += pooled[n * 192 + o] * fcW[cls * 192 + o];
  outp[idx] = acc;
}

// ---------------- host: replicate np.linspace + python round (ties-to-even) ----------------
static void make_segs(int T, int S, SegTable& tab, int& L){
  double step = (double)(T - 1) / (double)S;
  long long tv[51];
  for (int i = 0; i <= S; ++i){
    double v = 1.0 + step * (double)i;
    tv[i] = llrint(v);
  }
  L = 0;
  for (int s = 0; s < S; ++s){
    tab.st[s] = (int)tv[s] - 1;
    tab.en[s] = (int)tv[s + 1] - 1;
    int len = tab.en[s] - tab.st[s] + 1;
    if (len > L) L = len;
  }
  for (int s = S; s < 50; ++s){ tab.st[s] = 0; tab.en[s] = 0; }
  if (L > 4) L = 4;
}

extern "C" void kernel_launch(void* const* d_in, const int* in_sizes, int n_in,
                              void* d_out, int out_size, void* d_ws, size_t ws_size,
                              hipStream_t stream){
  const float* x         = (const float*)d_in[0];
  const float* data_bn_g = (const float*)d_in[2];
  const float* data_bn_b = (const float*)d_in[3];
  const float* A_powers1 = (const float*)d_in[4];
  const float* A_res1    = (const float*)d_in[5];
  const float* W1        = (const float*)d_in[6];
  const float* b1        = (const float*)d_in[7];
  const float* bn1_g     = (const float*)d_in[8];
  const float* bn1_b     = (const float*)d_in[9];
  const float* Wih1      = (const float*)d_in[10];
  const float* Whh1      = (const float*)d_in[11];
  const float* bih1      = (const float*)d_in[12];
  const float* bhh1      = (const float*)d_in[13];
  const float* bnseg1_g  = (const float*)d_in[14];
  const float* bnseg1_b  = (const float*)d_in[15];
  const float* A_powers2 = (const float*)d_in[16];
  const float* A_res2    = (const float*)d_in[17];
  const float* W2        = (const float*)d_in[18];
  const float* b2        = (const float*)d_in[19];
  const float* bn2_g     = (const float*)d_in[20];
  const float* bn2_b     = (const float*)d_in[21];
  const float* Wih2      = (const float*)d_in[22];
  const float* Whh2      = (const float*)d_in[23];
  const float* bih2      = (const float*)d_in[24];
  const float* bhh2      = (const float*)d_in[25];
  const float* bnseg2_g  = (const float*)d_in[26];
  const float* bnseg2_b  = (const float*)d_in[27];
  const float* fcW       = (const float*)d_in[28];
  const float* fcb       = (const float*)d_in[29];
  float* out = (float*)d_out;

  const int N = 2, C = 3, T = 100, V = 25, M = 2, NM = 4;
  const int C1 = 96, C2 = 192;
  const int S1 = 50, S2 = 30;
  const int B = 100;
  const int IN1 = 4752, IN2 = 18720;
  const int IN1P = 4800, IN2P = 18752;  // K padded to %64
  const int P1 = 4560, P2 = 18336;
  const int KG2 = 1248, KG2P = 1280;
  const int Z1 = 6, Z2 = 7, ZG = 4;     // Z1=6: 20x2x6=240 blocks (xp1 8ph); Z2=7: 12x3x7=252

  size_t off = 0;
  char* base = (char*)d_ws;
  auto alloc = [&](size_t nbytes) -> void* {
    off = (off + 255) & ~(size_t)255;
    void* p = base + off;
    off += nbytes;
    return p;
  };
  float* A1full = (float*)alloc(325 * 25 * 4);
  float* A2full = (float*)alloc(325 * 25 * 4);
  float* h1     = (float*)alloc((size_t)NM * C * T * V * 4);
  float* y1mat  = (float*)alloc((size_t)NM * T * V * C1 * 4);
  float* stats  = (float*)alloc(736 * 4);
  float* st1a = stats, *st1b = stats + 96;
  float* sg1a = stats + 192, *sg1b = stats + 242;
  float* st2a = stats + 292, *st2b = stats + 484;
  float* sg2a = stats + 676, *sg2b = stats + 706;
  float* l1out  = (float*)alloc((size_t)B * S1 * C1 * 4);
  bf16_t* A2mat = (bf16_t*)alloc((size_t)NM * S1 * V * KG2P * 2);
  float* y2mat  = (float*)alloc((size_t)NM * S1 * V * C2 * 4);
  float* l2out  = (float*)alloc((size_t)B * S2 * C2 * 4);
  float* pooled = (float*)alloc(2 * C2 * 4);
  float* bias1  = (float*)alloc(4 * C1 * 4);
  float* bias2  = (float*)alloc(4 * C2 * 4);
  half2_t* Wp1  = (half2_t*)alloc((size_t)(C1 / 2) * 4 * C1 * 4);
  half2_t* Wp2  = (half2_t*)alloc((size_t)(C2 / 2) * 4 * C2 * 4);
  bf16_t* Wih1b = (bf16_t*)alloc((size_t)4 * C1 * IN1P * 2);
  bf16_t* Wih2b = (bf16_t*)alloc((size_t)4 * C2 * IN2P * 2);
  bf16_t* W2b   = (bf16_t*)alloc((size_t)C2 * KG2P * 2);
  unsigned short* lut1 = (unsigned short*)alloc((size_t)P1 * 2);
  unsigned short* lut2 = (unsigned short*)alloc((size_t)P2 * 2);
  size_t pmax = (size_t)Z2 * 3000 * 768;
  {
    size_t p1s = (size_t)Z1 * 5000 * 384; if (p1s > pmax) pmax = p1s;
    size_t pgs = (size_t)ZG * 5000 * 192; if (pgs > pmax) pmax = pgs;
  }
  float* Pbuf = (float*)alloc(pmax * 4);
  bf16_t* feats = (bf16_t*)alloc((size_t)B * S2 * IN2P * 2);
  (void)ws_size; (void)in_sizes; (void)n_in; (void)out_size;

  // 1) prep: adds, whh packs, LUTs, stat zeros, A2mat K-pad
  prep_misc<<<625, 256, 0, stream>>>(A_powers1, A_res1, A1full, A_powers2, A_res2, A2full,
                                     bih1, bhh1, bias1, bih2, bhh2, bias2,
                                     Whh1, Wp1, Whh2, Wp2, lut1, lut2, stats, A2mat);
  // 2) weight bf16 conversion (one dispatch)
  {
    int c1 = 4 * C1 * (IN1P / 8);
    int c2 = 4 * C2 * (IN2P / 8);
    int c3 = C2 * (KG2P / 8);
    int tot = c1 + c2 + c3;
    f2bf_pad8_3<<<(tot + 255) / 256, 256, 0, stream>>>(Wih1, Wih1b, IN1, IN1P, c1,
                                                       Wih2, Wih2b, IN2, IN2P, c2,
                                                       W2, W2b, KG2, KG2P, c3);
  }

  // 3) data BN
  data_bn_kernel<<<M * V * C, 64, 0, stream>>>(x, data_bn_g, data_bn_b, h1, N, C, T, V, M);

  // 4) GCN1 fused (support + contract + stats)
  gcn1_fused<<<NM * T, 256, 0, stream>>>(A1full, h1, W1, b1, y1mat, st1a, st1b, T);

  SegTable seg1, seg2; int L1, L2;
  make_segs(T, S1, seg1, L1);
  make_segs(S1, S2, seg2, L2);

  // 5) feats1 (bn+relu inline)
  feats_bn_kernel<<<B * S1, 256, 0, stream>>>(y1mat, st1a, st1b, bn1_g, bn1_b, feats, seg1,
                                              (const unsigned int*)lut1, T, C1, S1, L1, P1, IN1P,
                                              NM * T * 25);
  // 6) xp1 GEMM (256^2 2-half-phase, XCD-chunked) + 7) lstm1 (+segstats fused)
  {
    int Mm = B * S1, Nn = 4 * C1;     // 5000 x 384, K = 4800 (75 ksteps)
    int GX = (Mm + 255) / 256, GY = (Nn + 255) / 256;   // 20 x 2 x 6 = 240 blocks
    gemm_mfma_nt_8ph<<<GX * GY * Z1, 512, 0, stream>>>(feats, Wih1b, Pbuf, Mm, Nn, IN1P,
                                                       GX, GY, Z1);
    lstm_kernel<48, 384, Z1><<<B, 384, 0, stream>>>(Pbuf, bias1, Wp1, l1out, sg1a, sg1b, S1, Mm * Nn);
  }

  // 8) support2 (+bnseg inline)
  {
    int tot = NM * S1 * 25 * 13 * 96;
    support2_bn<<<(tot + 255) / 256, 256, 0, stream>>>(A2full, l1out, sg1a, sg1b, bnseg1_g,
                                                       bnseg1_b, A2mat, S1, B * C1);
  }
  // 9) GCN2 GEMM + 10) reduce+bias+colstats
  {
    int Mm = NM * S1 * 25, Nn = C2;
    int GX = (Mm + 127) / 128, GY = (Nn + 127) / 128;
    gemm_mfma_nt_split<<<GX * GY * ZG, 256, 0, stream>>>(A2mat, W2b, Pbuf, Mm, Nn, KG2P,
                                                         GX, GY, ZG);
    int MN = Mm * Nn;
    reduce_split_bias_stats<<<(MN / 4 + 255) / 256, 256, 0, stream>>>(Pbuf, b2, y2mat, st2a, st2b,
                                                                      MN, Nn, ZG);
  }

  // 11) feats2 (bn+relu inline)
  feats_bn_kernel<<<B * S2, 256, 0, stream>>>(y2mat, st2a, st2b, bn2_g, bn2_b, feats, seg2,
                                              (const unsigned int*)lut2, S1, C2, S2, L2, P2, IN2P,
                                              NM * S1 * 25);
  // 12) xp2 GEMM (256^2 2-half-phase, XCD-chunked) + 13) lstm2 (+segstats fused)
  {
    int Mm = B * S2, Nn = 4 * C2;     // 3000 x 768, K = 18752 (293 K-steps)
    int GX = (Mm + 255) / 256, GY = (Nn + 255) / 256;   // 12 x 3 x 7 = 252 blocks
    gemm_mfma_nt_8ph<<<GX * GY * Z2, 512, 0, stream>>>(feats, Wih2b, Pbuf, Mm, Nn, IN2P,
                                                       GX, GY, Z2);
    lstm_kernel<96, 768, Z2><<<B, 768, 0, stream>>>(Pbuf, bias2, Wp2, l2out, sg2a, sg2b, S2, Mm * Nn);
  }

  // 14) pool, 15) fc
  pool_kernel<<<2 * C2, 64, 0, stream>>>(l2out, sg2a, sg2b, bnseg2_g, bnseg2_b, pooled, S2, C2, B * C2);
  fc_kernel<<<1, 128, 0, stream>>>(pooled, fcW, fcb, out);
}